// Round 1
// baseline (1968.245 us; speedup 1.0000x reference)
//
#include <hip/hip_runtime.h>
#include <hip/hip_bf16.h>

#define N_NODES 50000
#define N_EDGES 800000
#define DIM 128
#define NLAYERS 3

// ---------------- embedding gather: x[n,:] = emb[idx[n],:] ----------------
__global__ __launch_bounds__(256) void embed_kernel(
    const int* __restrict__ idx, const float* __restrict__ emb,
    float* __restrict__ x)
{
  int gid = blockIdx.x * 256 + threadIdx.x;   // one float4 per thread
  int n = gid >> 5;                           // 32 float4 per row
  int c = (gid & 31) << 2;
  if (n >= N_NODES) return;
  int e = idx[n];
  *(float4*)(x + (size_t)n * DIM + c) = *(const float4*)(emb + (size_t)e * DIM + c);
}

// ---------------- CSR build ----------------
__global__ __launch_bounds__(256) void hist_kernel(
    const int* __restrict__ e1, int* __restrict__ counts)
{
  int i = blockIdx.x * 256 + threadIdx.x;
  if (i < N_EDGES) atomicAdd(&counts[e1[i]], 1);
}

__global__ void scan_kernel(const int* __restrict__ counts,
                            int* __restrict__ offsets, int n)
{
  __shared__ int buf[1024];
  __shared__ int carry;
  int tid = threadIdx.x;
  if (tid == 0) carry = 0;
  __syncthreads();
  for (int base = 0; base < n; base += 1024) {
    int v = (base + tid < n) ? counts[base + tid] : 0;
    buf[tid] = v;
    __syncthreads();
    int sum = v;
    for (int off = 1; off < 1024; off <<= 1) {
      int t = (tid >= off) ? buf[tid - off] : 0;
      __syncthreads();
      sum += t;
      buf[tid] = sum;
      __syncthreads();
    }
    int c = carry;
    if (base + tid < n) offsets[base + tid] = c + sum - v;  // exclusive
    __syncthreads();
    if (tid == 1023) carry = c + buf[1023];
    __syncthreads();
  }
  if (tid == 0) offsets[n] = carry;
}

__global__ __launch_bounds__(256) void scatter_kernel(
    const int* __restrict__ e0, const int* __restrict__ e1,
    const int* __restrict__ offsets, int* __restrict__ fill,
    int* __restrict__ csr)
{
  int i = blockIdx.x * 256 + threadIdx.x;
  if (i >= N_EDGES) return;
  int d = e1[i];
  int pos = offsets[d] + atomicAdd(&fill[d], 1);
  csr[pos] = e0[i];
}

// ---------------- fp32 GEMM: out[N x ldo(block c0..c0+127)] = A[N x K] @ W[K x ldw] + bias ----------------
// 128x128 tile per block, 256 threads, 8x8 register tile per thread.
__global__ __launch_bounds__(256) void gemm_kernel(
    const float* __restrict__ A, int K,
    const float* __restrict__ W, int ldw,
    const float* __restrict__ bias,
    float* __restrict__ out, int ldo,
    int nrows, int relu)
{
  __shared__ float Wl[128 * 128];   // 64 KB
  __shared__ float Al[16 * 132];    // transposed A chunk [k][row], padded stride
  int tid = threadIdx.x;
  int c0 = blockIdx.y * 128;
  int r0 = blockIdx.x * 128;
  int tc = tid & 15;    // cols tc*8 .. +7
  int tr = tid >> 4;    // rows tr*8 .. +7
  float acc[8][8];
#pragma unroll
  for (int i = 0; i < 8; i++)
#pragma unroll
    for (int j = 0; j < 8; j++) acc[i][j] = 0.f;

  for (int kb = 0; kb < K; kb += 128) {
    __syncthreads();  // previous compute done before overwriting Wl
#pragma unroll
    for (int f = tid; f < 4096; f += 256) {   // 128x128 floats as float4
      int wr = f >> 5, wc = (f & 31) << 2;
      *(float4*)&Wl[wr * 128 + wc] =
          *(const float4*)&W[(size_t)(kb + wr) * ldw + c0 + wc];
    }
    for (int kc = 0; kc < 128; kc += 16) {
      if (kc) __syncthreads();   // previous compute done before overwriting Al
#pragma unroll
      for (int f = tid; f < 512; f += 256) {  // 128 rows x 16 k as float4
        int r = f >> 2, c4 = (f & 3) << 2;
        float4 av = make_float4(0.f, 0.f, 0.f, 0.f);
        if (r0 + r < nrows)
          av = *(const float4*)&A[(size_t)(r0 + r) * K + kb + kc + c4];
        Al[(c4 + 0) * 132 + r] = av.x;
        Al[(c4 + 1) * 132 + r] = av.y;
        Al[(c4 + 2) * 132 + r] = av.z;
        Al[(c4 + 3) * 132 + r] = av.w;
      }
      __syncthreads();
#pragma unroll
      for (int kk = 0; kk < 16; kk++) {
        float4 w0 = *(float4*)&Wl[(kc + kk) * 128 + tc * 8];
        float4 w1 = *(float4*)&Wl[(kc + kk) * 128 + tc * 8 + 4];
        float4 a0 = *(float4*)&Al[kk * 132 + tr * 8];
        float4 a1 = *(float4*)&Al[kk * 132 + tr * 8 + 4];
        float a[8] = {a0.x, a0.y, a0.z, a0.w, a1.x, a1.y, a1.z, a1.w};
        float w[8] = {w0.x, w0.y, w0.z, w0.w, w1.x, w1.y, w1.z, w1.w};
#pragma unroll
        for (int i = 0; i < 8; i++)
#pragma unroll
          for (int j = 0; j < 8; j++)
            acc[i][j] = fmaf(a[i], w[j], acc[i][j]);
      }
    }
  }
  // epilogue: bias (+relu), store
  float bv[8];
#pragma unroll
  for (int j = 0; j < 8; j++) bv[j] = bias[c0 + tc * 8 + j];
#pragma unroll
  for (int i = 0; i < 8; i++) {
    int r = r0 + tr * 8 + i;
    if (r < nrows) {
      float o[8];
#pragma unroll
      for (int j = 0; j < 8; j++) {
        o[j] = acc[i][j] + bv[j];
        if (relu) o[j] = fmaxf(o[j], 0.f);
      }
      *(float4*)&out[(size_t)r * ldo + c0 + tc * 8] = make_float4(o[0], o[1], o[2], o[3]);
      *(float4*)&out[(size_t)r * ldo + c0 + tc * 8 + 4] = make_float4(o[4], o[5], o[6], o[7]);
    }
  }
}

// ---------------- fused edge attention: one wave per destination node ----------------
// lane owns dims (2*lane, 2*lane+1); head = lane/8; per-head dot via 8-lane xor-shuffle.
__global__ __launch_bounds__(256) void attn_kernel(
    const float* __restrict__ q, const float* __restrict__ k,
    const float* __restrict__ v, const int* __restrict__ offsets,
    const int* __restrict__ csr, float* __restrict__ attn)
{
  int node = blockIdx.x * 4 + (threadIdx.x >> 6);
  int lane = threadIdx.x & 63;
  if (node >= N_NODES) return;
  float2 q2 = *(const float2*)(q + (size_t)node * DIM + lane * 2);
  float wx = 0.f, wy = 0.f, z = 0.f;
  int beg = offsets[node], end = offsets[node + 1];
  for (int j = beg; j < end; ++j) {
    int s = csr[j];
    float2 k2 = *(const float2*)(k + (size_t)s * DIM + lane * 2);
    float p = k2.x * q2.x + k2.y * q2.y;
    p += __shfl_xor(p, 1);
    p += __shfl_xor(p, 2);
    p += __shfl_xor(p, 4);   // now p = full head dot (same across the 8 lanes of the head)
    float sc = expf(fminf(fmaxf(p * 0.25f, -5.f), 5.f));  // scale = sqrt(16) = 4
    float2 v2 = *(const float2*)(v + (size_t)s * DIM + lane * 2);
    wx = fmaf(sc, v2.x, wx);
    wy = fmaf(sc, v2.y, wy);
    z += sc;
  }
  float inv = 1.f / (z + 1e-6f);
  *(float2*)(attn + (size_t)node * DIM + lane * 2) = make_float2(wx * inv, wy * inv);
}

// ---------------- x = LN(x + y) ----------------
__global__ __launch_bounds__(256) void ln_kernel(
    float* __restrict__ x, const float* __restrict__ y,
    const float* __restrict__ g, const float* __restrict__ b)
{
  int node = blockIdx.x * 4 + (threadIdx.x >> 6);
  int lane = threadIdx.x & 63;
  if (node >= N_NODES) return;
  size_t base = (size_t)node * DIM + lane * 2;
  float2 xv = *(float2*)(x + base);
  float2 yv = *(const float2*)(y + base);
  float s0 = xv.x + yv.x, s1 = xv.y + yv.y;
  float t = s0 + s1;
#pragma unroll
  for (int m = 1; m < 64; m <<= 1) t += __shfl_xor(t, m);
  float mean = t * (1.f / 128.f);
  float d0 = s0 - mean, d1 = s1 - mean;
  float vv = d0 * d0 + d1 * d1;
#pragma unroll
  for (int m = 1; m < 64; m <<= 1) vv += __shfl_xor(vv, m);
  float inv = rsqrtf(vv * (1.f / 128.f) + 1e-5f);
  float2 gv = *(const float2*)(g + lane * 2);
  float2 bv = *(const float2*)(b + lane * 2);
  *(float2*)(x + base) = make_float2(d0 * inv * gv.x + bv.x, d1 * inv * gv.y + bv.y);
}

// ---------------- column mean over nodes ----------------
__global__ __launch_bounds__(256) void colmean_kernel(
    const float* __restrict__ x, float* __restrict__ mean)
{
  int col = threadIdx.x & 127;
  int half = threadIdx.x >> 7;
  float acc = 0.f;
  for (int r = blockIdx.x * 2 + half; r < N_NODES; r += gridDim.x * 2)
    acc += x[(size_t)r * DIM + col];
  __shared__ float s[256];
  s[threadIdx.x] = acc;
  __syncthreads();
  if (threadIdx.x < 128) atomicAdd(&mean[col], s[threadIdx.x] + s[threadIdx.x + 128]);
}

// ---------------- readout MLP 128->64->32->10 (single block) ----------------
__global__ void readout_kernel(
    const float* __restrict__ mean,
    const float* __restrict__ mW0, const float* __restrict__ mb0,
    const float* __restrict__ mW1, const float* __restrict__ mb1,
    const float* __restrict__ mW2, const float* __restrict__ mb2,
    float* __restrict__ out)
{
  __shared__ float sx[128], h0[64], h1[32];
  int t = threadIdx.x;
  sx[t] = mean[t] * (1.f / (float)N_NODES);
  __syncthreads();
  if (t < 64) {
    float a = mb0[t];
    for (int i = 0; i < 128; i++) a = fmaf(sx[i], mW0[i * 64 + t], a);
    h0[t] = fmaxf(a, 0.f);
  }
  __syncthreads();
  if (t < 32) {
    float a = mb1[t];
    for (int i = 0; i < 64; i++) a = fmaf(h0[i], mW1[i * 32 + t], a);
    h1[t] = fmaxf(a, 0.f);
  }
  __syncthreads();
  if (t < 10) {
    float a = mb2[t];
    for (int i = 0; i < 32; i++) a = fmaf(h1[i], mW2[i * 10 + t], a);
    out[t] = a;
  }
}

extern "C" void kernel_launch(void* const* d_in, const int* in_sizes, int n_in,
                              void* d_out, int out_size, void* d_ws, size_t ws_size,
                              hipStream_t stream) {
  const int*   x_idx = (const int*)d_in[0];
  const int*   eidx  = (const int*)d_in[1];
  const float* emb   = (const float*)d_in[2];
  const float* Wq = (const float*)d_in[3];  const float* bq = (const float*)d_in[4];
  const float* Wk = (const float*)d_in[5];  const float* bk = (const float*)d_in[6];
  const float* Wv = (const float*)d_in[7];  const float* bv = (const float*)d_in[8];
  const float* Wo = (const float*)d_in[9];  const float* bo = (const float*)d_in[10];
  const float* g1 = (const float*)d_in[11]; const float* be1 = (const float*)d_in[12];
  const float* Wf1 = (const float*)d_in[13]; const float* bf1 = (const float*)d_in[14];
  const float* Wf2 = (const float*)d_in[15]; const float* bf2 = (const float*)d_in[16];
  const float* g2 = (const float*)d_in[17]; const float* be2 = (const float*)d_in[18];
  const float* mW0 = (const float*)d_in[19]; const float* mb0 = (const float*)d_in[20];
  const float* mW1 = (const float*)d_in[21]; const float* mb1 = (const float*)d_in[22];
  const float* mW2 = (const float*)d_in[23]; const float* mb2 = (const float*)d_in[24];
  float* out = (float*)d_out;

  const size_t NX = (size_t)N_NODES * DIM;
  float* x = (float*)d_ws;
  float* q = x + NX;
  float* k = q + NX;
  float* v = k + NX;
  float* y = v + NX;
  float* a = y + NX;
  float* ffh = q;                       // reuses q..k regions: N x 256, dead during FFN
  int* counts  = (int*)(a + NX);
  int* offsets = counts + N_NODES;
  int* fill    = offsets + N_NODES + 1;
  int* csr     = fill + N_NODES;
  float* meanb = (float*)(csr + N_EDGES);

  const int* e0 = eidx;
  const int* e1 = eidx + N_EDGES;

  hipMemsetAsync(counts, 0, N_NODES * sizeof(int), stream);
  hipMemsetAsync(fill, 0, N_NODES * sizeof(int), stream);
  hipMemsetAsync(meanb, 0, DIM * sizeof(float), stream);

  embed_kernel<<<(N_NODES * 32 + 255) / 256, 256, 0, stream>>>(x_idx, emb, x);
  hist_kernel<<<(N_EDGES + 255) / 256, 256, 0, stream>>>(e1, counts);
  scan_kernel<<<1, 1024, 0, stream>>>(counts, offsets, N_NODES);
  scatter_kernel<<<(N_EDGES + 255) / 256, 256, 0, stream>>>(e0, e1, offsets, fill, csr);

  dim3 gA((N_NODES + 127) / 128, 1);
  dim3 gF1((N_NODES + 127) / 128, 2);
  int nb4 = (N_NODES + 3) / 4;

  for (int l = 0; l < NLAYERS; ++l) {
    const float* Wq_l = Wq + (size_t)l * DIM * DIM;  const float* bq_l = bq + (size_t)l * DIM;
    const float* Wk_l = Wk + (size_t)l * DIM * DIM;  const float* bk_l = bk + (size_t)l * DIM;
    const float* Wv_l = Wv + (size_t)l * DIM * DIM;  const float* bv_l = bv + (size_t)l * DIM;
    const float* Wo_l = Wo + (size_t)l * DIM * DIM;  const float* bo_l = bo + (size_t)l * DIM;
    const float* Wf1_l = Wf1 + (size_t)l * DIM * 2 * DIM; const float* bf1_l = bf1 + (size_t)l * 2 * DIM;
    const float* Wf2_l = Wf2 + (size_t)l * 2 * DIM * DIM; const float* bf2_l = bf2 + (size_t)l * DIM;

    gemm_kernel<<<gA, 256, 0, stream>>>(x, DIM, Wq_l, DIM, bq_l, q, DIM, N_NODES, 0);
    gemm_kernel<<<gA, 256, 0, stream>>>(x, DIM, Wk_l, DIM, bk_l, k, DIM, N_NODES, 0);
    gemm_kernel<<<gA, 256, 0, stream>>>(x, DIM, Wv_l, DIM, bv_l, v, DIM, N_NODES, 0);
    attn_kernel<<<nb4, 256, 0, stream>>>(q, k, v, offsets, csr, a);
    gemm_kernel<<<gA, 256, 0, stream>>>(a, DIM, Wo_l, DIM, bo_l, y, DIM, N_NODES, 0);
    ln_kernel<<<nb4, 256, 0, stream>>>(x, y, g1 + (size_t)l * DIM, be1 + (size_t)l * DIM);
    gemm_kernel<<<gF1, 256, 0, stream>>>(y, DIM, Wf1_l, 2 * DIM, bf1_l, ffh, 2 * DIM, N_NODES, 1);
    gemm_kernel<<<gA, 256, 0, stream>>>(ffh, 2 * DIM, Wf2_l, DIM, bf2_l, a, DIM, N_NODES, 0);
    ln_kernel<<<nb4, 256, 0, stream>>>(x, a, g2 + (size_t)l * DIM, be2 + (size_t)l * DIM);
  }

  colmean_kernel<<<128, 256, 0, stream>>>(x, meanb);
  readout_kernel<<<1, 128, 0, stream>>>(meanb, mW0, mb0, mW1, mb1, mW2, mb2, out);
}

// Round 2
// 1192.781 us; speedup vs baseline: 1.6501x; 1.6501x over previous
//
#include <hip/hip_runtime.h>
#include <hip/hip_bf16.h>

#define N_NODES 50000
#define N_EDGES 800000
#define DIM 128
#define NLAYERS 3

typedef short bf16x8 __attribute__((ext_vector_type(8)));
typedef float floatx4 __attribute__((ext_vector_type(4)));

__device__ __forceinline__ unsigned short f2bf(float f) {
  unsigned int u = __builtin_bit_cast(unsigned int, f);
  return (unsigned short)((u + 0x7FFFu + ((u >> 16) & 1u)) >> 16);
}
// returns rounded-hi as float, sets hb to its bf16 bits
__device__ __forceinline__ float bfhi(float f, unsigned short& hb) {
  unsigned int u = __builtin_bit_cast(unsigned int, f);
  unsigned int r = (u + 0x7FFFu + ((u >> 16) & 1u)) & 0xFFFF0000u;
  hb = (unsigned short)(r >> 16);
  return __builtin_bit_cast(float, r);
}

// ---------------- embedding gather ----------------
__global__ __launch_bounds__(256) void embed_kernel(
    const int* __restrict__ idx, const float* __restrict__ emb,
    float* __restrict__ x)
{
  int gid = blockIdx.x * 256 + threadIdx.x;
  int n = gid >> 5;
  int c = (gid & 31) << 2;
  if (n >= N_NODES) return;
  int e = idx[n];
  *(float4*)(x + (size_t)n * DIM + c) = *(const float4*)(emb + (size_t)e * DIM + c);
}

// ---------------- CSR build ----------------
__global__ __launch_bounds__(256) void hist_kernel(
    const int* __restrict__ e1, int* __restrict__ counts)
{
  int i = blockIdx.x * 256 + threadIdx.x;
  if (i < N_EDGES) atomicAdd(&counts[e1[i]], 1);
}

// per-block exclusive scan of counts -> offsets(local); block totals -> bsums
__global__ __launch_bounds__(256) void scan_local(
    const int* __restrict__ counts, int* __restrict__ offsets,
    int* __restrict__ bsums)
{
  __shared__ int buf[256];
  int t = threadIdx.x;
  int i = blockIdx.x * 256 + t;
  int v = (i < N_NODES) ? counts[i] : 0;
  buf[t] = v;
  __syncthreads();
  int s = v;
#pragma unroll
  for (int off = 1; off < 256; off <<= 1) {
    int t2 = (t >= off) ? buf[t - off] : 0;
    __syncthreads();
    s += t2;
    buf[t] = s;
    __syncthreads();
  }
  if (i < N_NODES) offsets[i] = s - v;   // local exclusive
  if (t == 255) bsums[blockIdx.x] = s;
}

// single block: exclusive scan of block sums in place (nblk <= 256)
__global__ void scan_bsums(int* __restrict__ bsums, int nblk)
{
  __shared__ int buf[256];
  int t = threadIdx.x;
  int v = (t < nblk) ? bsums[t] : 0;
  buf[t] = v;
  __syncthreads();
  int s = v;
#pragma unroll
  for (int off = 1; off < 256; off <<= 1) {
    int t2 = (t >= off) ? buf[t - off] : 0;
    __syncthreads();
    s += t2;
    buf[t] = s;
    __syncthreads();
  }
  if (t < nblk) bsums[t] = s - v;  // exclusive
}

__global__ __launch_bounds__(256) void scan_add(
    int* __restrict__ offsets, const int* __restrict__ bsums)
{
  int i = blockIdx.x * 256 + threadIdx.x;
  if (i < N_NODES) offsets[i] += bsums[blockIdx.x];
  if (i == 0) offsets[N_NODES] = N_EDGES;
}

__global__ __launch_bounds__(256) void scatter_kernel(
    const int* __restrict__ e0, const int* __restrict__ e1,
    const int* __restrict__ offsets, int* __restrict__ fill,
    int* __restrict__ csr)
{
  int i = blockIdx.x * 256 + threadIdx.x;
  if (i >= N_EDGES) return;
  int d = e1[i];
  int pos = offsets[d] + atomicAdd(&fill[d], 1);
  csr[pos] = e0[i];
}

// ---------------- weight prep: W[L][K][N] fp32 -> frag-major hi/lo bf16 ----------------
// out layout per layer-matrix (2*K*N ushorts): plane p in {hi,lo}, frag (kq, n):
//   out[l*2*K*N + p*K*N + (kq*N + n)*8 + j] = bf16(W[l][kq*8+j][n])
__global__ __launch_bounds__(256) void prep_weights(
    const float* __restrict__ W, unsigned short* __restrict__ out,
    int K, int N, int L)
{
  int g = blockIdx.x * 256 + threadIdx.x;
  int fragsPerMat = (K / 8) * N;
  int total = L * fragsPerMat;
  if (g >= total) return;
  int l = g / fragsPerMat;
  int rem = g - l * fragsPerMat;
  int kq = rem / N;
  int n = rem - kq * N;
  const float* Wl = W + (size_t)l * K * N;
  unsigned short hi[8], lo[8];
#pragma unroll
  for (int j = 0; j < 8; j++) {
    float f = Wl[(size_t)(kq * 8 + j) * N + n];
    unsigned short hb;
    float hf = bfhi(f, hb);
    hi[j] = hb;
    lo[j] = f2bf(f - hf);
  }
  unsigned short* basehi = out + (size_t)l * 2 * K * N + (size_t)(kq * N + n) * 8;
  unsigned short* baselo = basehi + (size_t)K * N;
#pragma unroll
  for (int j = 0; j < 8; j++) { basehi[j] = hi[j]; baselo[j] = lo[j]; }
}

// ---------------- MFMA GEMM: out[nrows x N] = A[nrows x K] @ W + bias ----------------
// bf16 hi/lo split: product = hi*hi + hi*lo + lo*hi (~2^-17 relative error).
// W pre-split frag-major in global (Wp = hi plane; lo plane at +K*N ushorts).
// Block: 256 threads = 4 waves; wave does RT row-tiles x (NB/16) col-tiles of 16x16.
template<int K, int NB, int RT>
__global__ __launch_bounds__(256) void mfma_gemm(
    const float* __restrict__ A,
    const unsigned short* __restrict__ Wp, int N,
    const float* __restrict__ bias,
    float* __restrict__ out, int ldo, int nrows, int relu)
{
  constexpr int KQ = K / 8;
  constexpr int CT = NB / 16;
  __shared__ unsigned short SW[2 * KQ * NB * 8];  // 64 KB
  int tid = threadIdx.x;
  int c0 = blockIdx.y * NB;

  // stage W hi+lo col-block into LDS (vectorized 16B frag copies)
  {
    const int F = 2 * KQ * NB;
    const int planeStride = K * N;
#pragma unroll 4
    for (int f = tid; f < F; f += 256) {
      int p = f / (KQ * NB);
      int rem = f - p * (KQ * NB);
      int kq = rem / NB;
      int n = rem - kq * NB;
      *(bf16x8*)&SW[f * 8] =
          *(const bf16x8*)&Wp[(size_t)p * planeStride + (size_t)(kq * N + c0 + n) * 8];
    }
  }
  int wave = tid >> 6, lane = tid & 63;
  int quad = lane >> 4, l16 = lane & 15;
  int row0 = blockIdx.x * (RT * 64) + wave * (RT * 16);

  floatx4 acc[RT][CT];
#pragma unroll
  for (int rt = 0; rt < RT; rt++)
#pragma unroll
    for (int ct = 0; ct < CT; ct++) acc[rt][ct] = (floatx4)(0.f);

  const float* arow[RT];
#pragma unroll
  for (int rt = 0; rt < RT; rt++) {
    int r = row0 + rt * 16 + l16;
    r = min(r, nrows - 1);
    arow[rt] = A + (size_t)r * K + quad * 8;
  }
  __syncthreads();

#pragma unroll
  for (int kb = 0; kb < K / 32; ++kb) {
    bf16x8 ah[RT], al[RT];
#pragma unroll
    for (int rt = 0; rt < RT; rt++) {
      float4 f0 = *(const float4*)(arow[rt] + kb * 32);
      float4 f1 = *(const float4*)(arow[rt] + kb * 32 + 4);
      float fv[8] = {f0.x, f0.y, f0.z, f0.w, f1.x, f1.y, f1.z, f1.w};
#pragma unroll
      for (int j = 0; j < 8; j++) {
        unsigned short hb;
        float hf = bfhi(fv[j], hb);
        ah[rt][j] = (short)hb;
        al[rt][j] = (short)f2bf(fv[j] - hf);
      }
    }
#pragma unroll
    for (int ct = 0; ct < CT; ct++) {
      int base = ((kb * 4 + quad) * NB + ct * 16 + l16) * 8;
      bf16x8 bh = *(bf16x8*)&SW[base];
      bf16x8 bl = *(bf16x8*)&SW[KQ * NB * 8 + base];
#pragma unroll
      for (int rt = 0; rt < RT; rt++) {
        acc[rt][ct] = __builtin_amdgcn_mfma_f32_16x16x32_bf16(ah[rt], bh, acc[rt][ct], 0, 0, 0);
        acc[rt][ct] = __builtin_amdgcn_mfma_f32_16x16x32_bf16(ah[rt], bl, acc[rt][ct], 0, 0, 0);
        acc[rt][ct] = __builtin_amdgcn_mfma_f32_16x16x32_bf16(al[rt], bh, acc[rt][ct], 0, 0, 0);
      }
    }
  }

  // epilogue: bias (+relu), store (C/D layout: col=lane&15, row=quad*4+reg)
#pragma unroll
  for (int ct = 0; ct < CT; ct++) {
    int col = c0 + ct * 16 + l16;
    float bv = bias[col];
#pragma unroll
    for (int rt = 0; rt < RT; rt++) {
#pragma unroll
      for (int i = 0; i < 4; i++) {
        int r = row0 + rt * 16 + quad * 4 + i;
        if (r < nrows) {
          float o = acc[rt][ct][i] + bv;
          if (relu) o = fmaxf(o, 0.f);
          out[(size_t)r * ldo + col] = o;
        }
      }
    }
  }
}

// ---------------- fused edge attention: one wave per destination node ----------------
__global__ __launch_bounds__(256) void attn_kernel(
    const float* __restrict__ q, const float* __restrict__ k,
    const float* __restrict__ v, const int* __restrict__ offsets,
    const int* __restrict__ csr, float* __restrict__ attn)
{
  int node = blockIdx.x * 4 + (threadIdx.x >> 6);
  int lane = threadIdx.x & 63;
  if (node >= N_NODES) return;
  float2 q2 = *(const float2*)(q + (size_t)node * DIM + lane * 2);
  float wx = 0.f, wy = 0.f, z = 0.f;
  int beg = offsets[node], end = offsets[node + 1];
  for (int j = beg; j < end; ++j) {
    int s = csr[j];
    float2 k2 = *(const float2*)(k + (size_t)s * DIM + lane * 2);
    float p = k2.x * q2.x + k2.y * q2.y;
    p += __shfl_xor(p, 1);
    p += __shfl_xor(p, 2);
    p += __shfl_xor(p, 4);
    float sc = __expf(fminf(fmaxf(p * 0.25f, -5.f), 5.f));
    float2 v2 = *(const float2*)(v + (size_t)s * DIM + lane * 2);
    wx = fmaf(sc, v2.x, wx);
    wy = fmaf(sc, v2.y, wy);
    z += sc;
  }
  float inv = 1.f / (z + 1e-6f);
  *(float2*)(attn + (size_t)node * DIM + lane * 2) = make_float2(wx * inv, wy * inv);
}

// ---------------- x = LN(x + y) ----------------
__global__ __launch_bounds__(256) void ln_kernel(
    float* __restrict__ x, const float* __restrict__ y,
    const float* __restrict__ g, const float* __restrict__ b)
{
  int node = blockIdx.x * 4 + (threadIdx.x >> 6);
  int lane = threadIdx.x & 63;
  if (node >= N_NODES) return;
  size_t base = (size_t)node * DIM + lane * 2;
  float2 xv = *(float2*)(x + base);
  float2 yv = *(const float2*)(y + base);
  float s0 = xv.x + yv.x, s1 = xv.y + yv.y;
  float t = s0 + s1;
#pragma unroll
  for (int m = 1; m < 64; m <<= 1) t += __shfl_xor(t, m);
  float mean = t * (1.f / 128.f);
  float d0 = s0 - mean, d1 = s1 - mean;
  float vv = d0 * d0 + d1 * d1;
#pragma unroll
  for (int m = 1; m < 64; m <<= 1) vv += __shfl_xor(vv, m);
  float inv = rsqrtf(vv * (1.f / 128.f) + 1e-5f);
  float2 gv = *(const float2*)(g + lane * 2);
  float2 bv = *(const float2*)(b + lane * 2);
  *(float2*)(x + base) = make_float2(d0 * inv * gv.x + bv.x, d1 * inv * gv.y + bv.y);
}

// ---------------- column mean over nodes ----------------
__global__ __launch_bounds__(256) void colmean_kernel(
    const float* __restrict__ x, float* __restrict__ mean)
{
  int col = threadIdx.x & 127;
  int half = threadIdx.x >> 7;
  float acc = 0.f;
  for (int r = blockIdx.x * 2 + half; r < N_NODES; r += gridDim.x * 2)
    acc += x[(size_t)r * DIM + col];
  __shared__ float s[256];
  s[threadIdx.x] = acc;
  __syncthreads();
  if (threadIdx.x < 128) atomicAdd(&mean[col], s[threadIdx.x] + s[threadIdx.x + 128]);
}

// ---------------- readout MLP 128->64->32->10 ----------------
__global__ void readout_kernel(
    const float* __restrict__ mean,
    const float* __restrict__ mW0, const float* __restrict__ mb0,
    const float* __restrict__ mW1, const float* __restrict__ mb1,
    const float* __restrict__ mW2, const float* __restrict__ mb2,
    float* __restrict__ out)
{
  __shared__ float sx[128], h0[64], h1[32];
  int t = threadIdx.x;
  sx[t] = mean[t] * (1.f / (float)N_NODES);
  __syncthreads();
  if (t < 64) {
    float a = mb0[t];
    for (int i = 0; i < 128; i++) a = fmaf(sx[i], mW0[i * 64 + t], a);
    h0[t] = fmaxf(a, 0.f);
  }
  __syncthreads();
  if (t < 32) {
    float a = mb1[t];
    for (int i = 0; i < 64; i++) a = fmaf(h0[i], mW1[i * 32 + t], a);
    h1[t] = fmaxf(a, 0.f);
  }
  __syncthreads();
  if (t < 10) {
    float a = mb2[t];
    for (int i = 0; i < 32; i++) a = fmaf(h1[i], mW2[i * 10 + t], a);
    out[t] = a;
  }
}

extern "C" void kernel_launch(void* const* d_in, const int* in_sizes, int n_in,
                              void* d_out, int out_size, void* d_ws, size_t ws_size,
                              hipStream_t stream) {
  const int*   x_idx = (const int*)d_in[0];
  const int*   eidx  = (const int*)d_in[1];
  const float* emb   = (const float*)d_in[2];
  const float* Wq = (const float*)d_in[3];  const float* bq = (const float*)d_in[4];
  const float* Wk = (const float*)d_in[5];  const float* bk = (const float*)d_in[6];
  const float* Wv = (const float*)d_in[7];  const float* bv = (const float*)d_in[8];
  const float* Wo = (const float*)d_in[9];  const float* bo = (const float*)d_in[10];
  const float* g1 = (const float*)d_in[11]; const float* be1 = (const float*)d_in[12];
  const float* Wf1 = (const float*)d_in[13]; const float* bf1 = (const float*)d_in[14];
  const float* Wf2 = (const float*)d_in[15]; const float* bf2 = (const float*)d_in[16];
  const float* g2 = (const float*)d_in[17]; const float* be2 = (const float*)d_in[18];
  const float* mW0 = (const float*)d_in[19]; const float* mb0 = (const float*)d_in[20];
  const float* mW1 = (const float*)d_in[21]; const float* mb1 = (const float*)d_in[22];
  const float* mW2 = (const float*)d_in[23]; const float* mb2 = (const float*)d_in[24];
  float* out = (float*)d_out;

  const size_t NX = (size_t)N_NODES * DIM;
  float* x = (float*)d_ws;
  float* q = x + NX;
  float* k = q + NX;
  float* v = k + NX;
  float* y = v + NX;
  float* a = y + NX;
  float* ffh = q;                       // N x 256, reuses q,k (dead during FFN)

  // prepped weights (frag-major hi/lo bf16), 786432 ushorts = 1.5 MB
  unsigned short* wp = (unsigned short*)(a + NX);
  unsigned short* wq_p = wp;
  unsigned short* wk_p = wq_p + 3 * 2 * 128 * 128;
  unsigned short* wv_p = wk_p + 3 * 2 * 128 * 128;
  unsigned short* wo_p = wv_p + 3 * 2 * 128 * 128;
  unsigned short* wf1_p = wo_p + 3 * 2 * 128 * 128;
  unsigned short* wf2_p = wf1_p + 3 * 2 * 128 * 256;
  unsigned short* wend = wf2_p + 3 * 2 * 256 * 128;

  int* counts  = (int*)wend;
  int* offsets = counts + N_NODES;
  int* fill    = offsets + N_NODES + 1;
  int* bsums   = fill + N_NODES;
  int* csr     = bsums + 256;
  float* meanb = (float*)(csr + N_EDGES);

  const int* e0 = eidx;
  const int* e1 = eidx + N_EDGES;

  hipMemsetAsync(counts, 0, N_NODES * sizeof(int), stream);
  hipMemsetAsync(fill, 0, N_NODES * sizeof(int), stream);
  hipMemsetAsync(meanb, 0, DIM * sizeof(float), stream);

  // weight prep (once per call)
  prep_weights<<<(3 * 16 * 128 + 255) / 256, 256, 0, stream>>>(Wq, wq_p, 128, 128, 3);
  prep_weights<<<(3 * 16 * 128 + 255) / 256, 256, 0, stream>>>(Wk, wk_p, 128, 128, 3);
  prep_weights<<<(3 * 16 * 128 + 255) / 256, 256, 0, stream>>>(Wv, wv_p, 128, 128, 3);
  prep_weights<<<(3 * 16 * 128 + 255) / 256, 256, 0, stream>>>(Wo, wo_p, 128, 128, 3);
  prep_weights<<<(3 * 16 * 256 + 255) / 256, 256, 0, stream>>>(Wf1, wf1_p, 128, 256, 3);
  prep_weights<<<(3 * 32 * 128 + 255) / 256, 256, 0, stream>>>(Wf2, wf2_p, 256, 128, 3);

  embed_kernel<<<(N_NODES * 32 + 255) / 256, 256, 0, stream>>>(x_idx, emb, x);
  hist_kernel<<<(N_EDGES + 255) / 256, 256, 0, stream>>>(e1, counts);
  int nblk = (N_NODES + 255) / 256;  // 196
  scan_local<<<nblk, 256, 0, stream>>>(counts, offsets, bsums);
  scan_bsums<<<1, 256, 0, stream>>>(bsums, nblk);
  scan_add<<<nblk, 256, 0, stream>>>(offsets, bsums);
  scatter_kernel<<<(N_EDGES + 255) / 256, 256, 0, stream>>>(e0, e1, offsets, fill, csr);

  dim3 g128((N_NODES + 127) / 128, 1);     // RT=2 config: 128 rows/block
  dim3 gF1((N_NODES + 127) / 128, 2);      // 256 cols => y=2
  dim3 gF2((N_NODES + 255) / 256, 2);      // RT=4 config: 256 rows/block, 64-col blocks
  int nb4 = (N_NODES + 3) / 4;

  for (int l = 0; l < NLAYERS; ++l) {
    const unsigned short* wq_l = wq_p + (size_t)l * 2 * 128 * 128;
    const unsigned short* wk_l = wk_p + (size_t)l * 2 * 128 * 128;
    const unsigned short* wv_l = wv_p + (size_t)l * 2 * 128 * 128;
    const unsigned short* wo_l = wo_p + (size_t)l * 2 * 128 * 128;
    const unsigned short* wf1_l = wf1_p + (size_t)l * 2 * 128 * 256;
    const unsigned short* wf2_l = wf2_p + (size_t)l * 2 * 256 * 128;
    const float* bq_l = bq + (size_t)l * DIM;
    const float* bk_l = bk + (size_t)l * DIM;
    const float* bv_l = bv + (size_t)l * DIM;
    const float* bo_l = bo + (size_t)l * DIM;
    const float* bf1_l = bf1 + (size_t)l * 2 * DIM;
    const float* bf2_l = bf2 + (size_t)l * DIM;

    mfma_gemm<128, 128, 2><<<g128, 256, 0, stream>>>(x, wq_l, 128, bq_l, q, DIM, N_NODES, 0);
    mfma_gemm<128, 128, 2><<<g128, 256, 0, stream>>>(x, wk_l, 128, bk_l, k, DIM, N_NODES, 0);
    mfma_gemm<128, 128, 2><<<g128, 256, 0, stream>>>(x, wv_l, 128, bv_l, v, DIM, N_NODES, 0);
    attn_kernel<<<nb4, 256, 0, stream>>>(q, k, v, offsets, csr, a);
    mfma_gemm<128, 128, 2><<<g128, 256, 0, stream>>>(a, wo_l, 128, bo_l, y, DIM, N_NODES, 0);
    ln_kernel<<<nb4, 256, 0, stream>>>(x, y, g1 + (size_t)l * DIM, be1 + (size_t)l * DIM);
    mfma_gemm<128, 128, 2><<<gF1, 256, 0, stream>>>(y, wf1_l, 256, bf1_l, ffh, 2 * DIM, N_NODES, 1);
    mfma_gemm<256, 64, 4><<<gF2, 256, 0, stream>>>(ffh, wf2_l, 128, bf2_l, a, DIM, N_NODES, 0);
    ln_kernel<<<nb4, 256, 0, stream>>>(x, a, g2 + (size_t)l * DIM, be2 + (size_t)l * DIM);
  }

  colmean_kernel<<<128, 256, 0, stream>>>(x, meanb);
  readout_kernel<<<1, 128, 0, stream>>>(meanb, mW0, mb0, mW1, mb1, mW2, mb2, out);
}

// Round 3
// 870.758 us; speedup vs baseline: 2.2604x; 1.3698x over previous
//
#include <hip/hip_runtime.h>
#include <hip/hip_bf16.h>

#define N_NODES 50000
#define N_EDGES 800000
#define DIM 128
#define NLAYERS 3

typedef short bf16x8 __attribute__((ext_vector_type(8)));
typedef float floatx4 __attribute__((ext_vector_type(4)));

__device__ __forceinline__ unsigned short f2bf(float f) {
  unsigned int u = __builtin_bit_cast(unsigned int, f);
  return (unsigned short)((u + 0x7FFFu + ((u >> 16) & 1u)) >> 16);
}
__device__ __forceinline__ float bfhi(float f, unsigned short& hb) {
  unsigned int u = __builtin_bit_cast(unsigned int, f);
  unsigned int r = (u + 0x7FFFu + ((u >> 16) & 1u)) & 0xFFFF0000u;
  hb = (unsigned short)(r >> 16);
  return __builtin_bit_cast(float, r);
}
__device__ __forceinline__ float2 bf2f2(unsigned int u) {
  float lo = __builtin_bit_cast(float, u << 16);
  float hi = __builtin_bit_cast(float, u & 0xFFFF0000u);
  return make_float2(lo, hi);
}

// ---------------- embedding gather ----------------
__global__ __launch_bounds__(256) void embed_kernel(
    const int* __restrict__ idx, const float* __restrict__ emb,
    float* __restrict__ x)
{
  int gid = blockIdx.x * 256 + threadIdx.x;
  int n = gid >> 5;
  int c = (gid & 31) << 2;
  if (n >= N_NODES) return;
  int e = idx[n];
  *(float4*)(x + (size_t)n * DIM + c) = *(const float4*)(emb + (size_t)e * DIM + c);
}

// ---------------- CSR build ----------------
__global__ __launch_bounds__(256) void hist_kernel(
    const int* __restrict__ e1, int* __restrict__ counts)
{
  int i = blockIdx.x * 256 + threadIdx.x;
  if (i < N_EDGES) atomicAdd(&counts[e1[i]], 1);
}

__global__ __launch_bounds__(256) void scan_local(
    const int* __restrict__ counts, int* __restrict__ offsets,
    int* __restrict__ bsums)
{
  __shared__ int buf[256];
  int t = threadIdx.x;
  int i = blockIdx.x * 256 + t;
  int v = (i < N_NODES) ? counts[i] : 0;
  buf[t] = v;
  __syncthreads();
  int s = v;
#pragma unroll
  for (int off = 1; off < 256; off <<= 1) {
    int t2 = (t >= off) ? buf[t - off] : 0;
    __syncthreads();
    s += t2;
    buf[t] = s;
    __syncthreads();
  }
  if (i < N_NODES) offsets[i] = s - v;
  if (t == 255) bsums[blockIdx.x] = s;
}

__global__ void scan_bsums(int* __restrict__ bsums, int nblk)
{
  __shared__ int buf[256];
  int t = threadIdx.x;
  int v = (t < nblk) ? bsums[t] : 0;
  buf[t] = v;
  __syncthreads();
  int s = v;
#pragma unroll
  for (int off = 1; off < 256; off <<= 1) {
    int t2 = (t >= off) ? buf[t - off] : 0;
    __syncthreads();
    s += t2;
    buf[t] = s;
    __syncthreads();
  }
  if (t < nblk) bsums[t] = s - v;
}

__global__ __launch_bounds__(256) void scan_add(
    int* __restrict__ offsets, const int* __restrict__ bsums)
{
  int i = blockIdx.x * 256 + threadIdx.x;
  if (i < N_NODES) offsets[i] += bsums[blockIdx.x];
  if (i == 0) offsets[N_NODES] = N_EDGES;
}

__global__ __launch_bounds__(256) void scatter_kernel(
    const int* __restrict__ e0, const int* __restrict__ e1,
    const int* __restrict__ offsets, int* __restrict__ fill,
    int* __restrict__ csr)
{
  int i = blockIdx.x * 256 + threadIdx.x;
  if (i >= N_EDGES) return;
  int d = e1[i];
  int pos = offsets[d] + atomicAdd(&fill[d], 1);
  csr[pos] = e0[i];
}

// ---------------- weight prep: W[L][K][Nsrc] fp32 -> frag-major hi/lo bf16 ----------------
// combined layout width Ndst, source placed at col offset c0.
__global__ __launch_bounds__(256) void prep_weights(
    const float* __restrict__ W, unsigned short* __restrict__ out,
    int K, int Nsrc, int Ndst, int c0, int L)
{
  int g = blockIdx.x * 256 + threadIdx.x;
  int fragsPerMat = (K / 8) * Nsrc;
  int total = L * fragsPerMat;
  if (g >= total) return;
  int l = g / fragsPerMat;
  int rem = g - l * fragsPerMat;
  int kq = rem / Nsrc;
  int n = rem - kq * Nsrc;
  const float* Wl = W + (size_t)l * K * Nsrc;
  unsigned short* basehi = out + (size_t)l * 2 * K * Ndst + (size_t)(kq * Ndst + c0 + n) * 8;
  unsigned short* baselo = basehi + (size_t)K * Ndst;
#pragma unroll
  for (int j = 0; j < 8; j++) {
    float f = Wl[(size_t)(kq * 8 + j) * Nsrc + n];
    unsigned short hb;
    float hf = bfhi(f, hb);
    basehi[j] = hb;
    baselo[j] = f2bf(f - hf);
  }
}

// ================ GEMM core macro pieces (K=128 chunked staging) ================
// All GEMMs: block = 256 thr = 4 waves, 128 rows/block, NB=128 cols, RT=2.
// bf16 hi/lo split A (from fp32) x pre-split W: hh + hl + lh.

// ---------------- generic fp32-out GEMM (used for FFN1, N=256) ----------------
template<int K>
__global__ __launch_bounds__(256) void mfma_gemm(
    const float* __restrict__ A,
    const unsigned short* __restrict__ Wp, int N,
    const float* __restrict__ bias,
    float* __restrict__ out, int ldo, int nrows, int relu)
{
  constexpr int CT = 8;
  __shared__ unsigned short SW[2 * 16 * 128 * 8];  // 64 KB chunk
  int tid = threadIdx.x;
  int c0 = blockIdx.y * 128;
  int wave = tid >> 6, lane = tid & 63;
  int quad = lane >> 4, l16 = lane & 15;
  int row0 = blockIdx.x * 128 + wave * 32;

  floatx4 acc[2][CT];
#pragma unroll
  for (int rt = 0; rt < 2; rt++)
#pragma unroll
    for (int ct = 0; ct < CT; ct++) acc[rt][ct] = (floatx4)(0.f);

  const float* arow[2];
#pragma unroll
  for (int rt = 0; rt < 2; rt++) {
    int r = min(row0 + rt * 16 + l16, nrows - 1);
    arow[rt] = A + (size_t)r * K + quad * 8;
  }
  const int planeStride = K * N;

  for (int kc0 = 0; kc0 < K; kc0 += 128) {
    __syncthreads();
#pragma unroll 4
    for (int f = tid; f < 2 * 16 * 128; f += 256) {
      int p = f >> 11;                 // f / 2048
      int rem = f & 2047;
      int kq = rem >> 7;               // rem / 128
      int n = rem & 127;
      *(bf16x8*)&SW[f * 8] =
          *(const bf16x8*)&Wp[(size_t)p * planeStride +
                              (size_t)((kc0 / 8 + kq) * N + c0 + n) * 8];
    }
    __syncthreads();
#pragma unroll
    for (int kb = 0; kb < 4; ++kb) {
      bf16x8 ah[2], al[2];
#pragma unroll
      for (int rt = 0; rt < 2; rt++) {
        float4 f0 = *(const float4*)(arow[rt] + kc0 + kb * 32);
        float4 f1 = *(const float4*)(arow[rt] + kc0 + kb * 32 + 4);
        float fv[8] = {f0.x, f0.y, f0.z, f0.w, f1.x, f1.y, f1.z, f1.w};
#pragma unroll
        for (int j = 0; j < 8; j++) {
          unsigned short hb;
          float hf = bfhi(fv[j], hb);
          ah[rt][j] = (short)hb;
          al[rt][j] = (short)f2bf(fv[j] - hf);
        }
      }
#pragma unroll
      for (int ct = 0; ct < CT; ct++) {
        int base = ((kb * 4 + quad) * 128 + ct * 16 + l16) * 8;
        bf16x8 bh = *(bf16x8*)&SW[base];
        bf16x8 bl = *(bf16x8*)&SW[16 * 128 * 8 + base];
#pragma unroll
        for (int rt = 0; rt < 2; rt++) {
          acc[rt][ct] = __builtin_amdgcn_mfma_f32_16x16x32_bf16(ah[rt], bh, acc[rt][ct], 0, 0, 0);
          acc[rt][ct] = __builtin_amdgcn_mfma_f32_16x16x32_bf16(ah[rt], bl, acc[rt][ct], 0, 0, 0);
          acc[rt][ct] = __builtin_amdgcn_mfma_f32_16x16x32_bf16(al[rt], bh, acc[rt][ct], 0, 0, 0);
        }
      }
    }
  }
#pragma unroll
  for (int ct = 0; ct < CT; ct++) {
    int col = c0 + ct * 16 + l16;
    float bv = bias[col];
#pragma unroll
    for (int rt = 0; rt < 2; rt++)
#pragma unroll
      for (int i = 0; i < 4; i++) {
        int r = row0 + rt * 16 + quad * 4 + i;
        if (r < nrows) {
          float o = acc[rt][ct][i] + bv;
          if (relu) o = fmaxf(o, 0.f);
          out[(size_t)r * ldo + col] = o;
        }
      }
  }
}

// ---------------- QKV GEMM: N=384 combined W, bf16 packed output ----------------
__global__ __launch_bounds__(256) void mfma_gemm_qkv(
    const float* __restrict__ A,
    const unsigned short* __restrict__ Wp,
    const float* __restrict__ bq, const float* __restrict__ bk,
    const float* __restrict__ bv,
    unsigned short* __restrict__ out, int nrows)
{
  constexpr int K = 128, N = 384, CT = 8;
  __shared__ unsigned short SW[2 * 16 * 128 * 8];
  int tid = threadIdx.x;
  int c0 = blockIdx.y * 128;
  const float* bias = (blockIdx.y == 0) ? bq : (blockIdx.y == 1) ? bk : bv;
  int wave = tid >> 6, lane = tid & 63;
  int quad = lane >> 4, l16 = lane & 15;
  int row0 = blockIdx.x * 128 + wave * 32;

  floatx4 acc[2][CT];
#pragma unroll
  for (int rt = 0; rt < 2; rt++)
#pragma unroll
    for (int ct = 0; ct < CT; ct++) acc[rt][ct] = (floatx4)(0.f);

  const float* arow[2];
#pragma unroll
  for (int rt = 0; rt < 2; rt++) {
    int r = min(row0 + rt * 16 + l16, nrows - 1);
    arow[rt] = A + (size_t)r * K + quad * 8;
  }
  {
    __syncthreads();
#pragma unroll 4
    for (int f = tid; f < 2 * 16 * 128; f += 256) {
      int p = f >> 11;
      int rem = f & 2047;
      int kq = rem >> 7;
      int n = rem & 127;
      *(bf16x8*)&SW[f * 8] =
          *(const bf16x8*)&Wp[(size_t)p * (K * N) + (size_t)(kq * N + c0 + n) * 8];
    }
    __syncthreads();
#pragma unroll
    for (int kb = 0; kb < 4; ++kb) {
      bf16x8 ah[2], al[2];
#pragma unroll
      for (int rt = 0; rt < 2; rt++) {
        float4 f0 = *(const float4*)(arow[rt] + kb * 32);
        float4 f1 = *(const float4*)(arow[rt] + kb * 32 + 4);
        float fv[8] = {f0.x, f0.y, f0.z, f0.w, f1.x, f1.y, f1.z, f1.w};
#pragma unroll
        for (int j = 0; j < 8; j++) {
          unsigned short hb;
          float hf = bfhi(fv[j], hb);
          ah[rt][j] = (short)hb;
          al[rt][j] = (short)f2bf(fv[j] - hf);
        }
      }
#pragma unroll
      for (int ct = 0; ct < CT; ct++) {
        int base = ((kb * 4 + quad) * 128 + ct * 16 + l16) * 8;
        bf16x8 bh = *(bf16x8*)&SW[base];
        bf16x8 bl = *(bf16x8*)&SW[16 * 128 * 8 + base];
#pragma unroll
        for (int rt = 0; rt < 2; rt++) {
          acc[rt][ct] = __builtin_amdgcn_mfma_f32_16x16x32_bf16(ah[rt], bh, acc[rt][ct], 0, 0, 0);
          acc[rt][ct] = __builtin_amdgcn_mfma_f32_16x16x32_bf16(ah[rt], bl, acc[rt][ct], 0, 0, 0);
          acc[rt][ct] = __builtin_amdgcn_mfma_f32_16x16x32_bf16(al[rt], bh, acc[rt][ct], 0, 0, 0);
        }
      }
    }
  }
#pragma unroll
  for (int ct = 0; ct < CT; ct++) {
    float bvv = bias[ct * 16 + l16];
    int col = c0 + ct * 16 + l16;
#pragma unroll
    for (int rt = 0; rt < 2; rt++)
#pragma unroll
      for (int i = 0; i < 4; i++) {
        int r = row0 + rt * 16 + quad * 4 + i;
        if (r < nrows)
          out[(size_t)r * 384 + col] = f2bf(acc[rt][ct][i] + bvv);
      }
  }
}

// ---------------- GEMM + fused residual LayerNorm (N=128) ----------------
// y = A@W + bias; if STORE_Y: yout = y;  x = LN(x + y) * g + b
template<int K, bool STORE_Y>
__global__ __launch_bounds__(256) void mfma_gemm_ln(
    const float* __restrict__ A,
    const unsigned short* __restrict__ Wp,
    const float* __restrict__ bias,
    float* __restrict__ x, float* __restrict__ yout,
    const float* __restrict__ g, const float* __restrict__ b, int nrows)
{
  constexpr int N = 128, CT = 8;
  __shared__ unsigned short SW[2 * 16 * 128 * 8];
  int tid = threadIdx.x;
  int wave = tid >> 6, lane = tid & 63;
  int quad = lane >> 4, l16 = lane & 15;
  int row0 = blockIdx.x * 128 + wave * 32;

  floatx4 acc[2][CT];
#pragma unroll
  for (int rt = 0; rt < 2; rt++)
#pragma unroll
    for (int ct = 0; ct < CT; ct++) acc[rt][ct] = (floatx4)(0.f);

  const float* arow[2];
#pragma unroll
  for (int rt = 0; rt < 2; rt++) {
    int r = min(row0 + rt * 16 + l16, nrows - 1);
    arow[rt] = A + (size_t)r * K + quad * 8;
  }
  const int planeStride = K * N;

  for (int kc0 = 0; kc0 < K; kc0 += 128) {
    __syncthreads();
#pragma unroll 4
    for (int f = tid; f < 2 * 16 * 128; f += 256) {
      int p = f >> 11;
      int rem = f & 2047;
      int kq = rem >> 7;
      int n = rem & 127;
      *(bf16x8*)&SW[f * 8] =
          *(const bf16x8*)&Wp[(size_t)p * planeStride +
                              (size_t)((kc0 / 8 + kq) * N + n) * 8];
    }
    __syncthreads();
#pragma unroll
    for (int kb = 0; kb < 4; ++kb) {
      bf16x8 ah[2], al[2];
#pragma unroll
      for (int rt = 0; rt < 2; rt++) {
        float4 f0 = *(const float4*)(arow[rt] + kc0 + kb * 32);
        float4 f1 = *(const float4*)(arow[rt] + kc0 + kb * 32 + 4);
        float fv[8] = {f0.x, f0.y, f0.z, f0.w, f1.x, f1.y, f1.z, f1.w};
#pragma unroll
        for (int j = 0; j < 8; j++) {
          unsigned short hb;
          float hf = bfhi(fv[j], hb);
          ah[rt][j] = (short)hb;
          al[rt][j] = (short)f2bf(fv[j] - hf);
        }
      }
#pragma unroll
      for (int ct = 0; ct < CT; ct++) {
        int base = ((kb * 4 + quad) * 128 + ct * 16 + l16) * 8;
        bf16x8 bh = *(bf16x8*)&SW[base];
        bf16x8 bl = *(bf16x8*)&SW[16 * 128 * 8 + base];
#pragma unroll
        for (int rt = 0; rt < 2; rt++) {
          acc[rt][ct] = __builtin_amdgcn_mfma_f32_16x16x32_bf16(ah[rt], bh, acc[rt][ct], 0, 0, 0);
          acc[rt][ct] = __builtin_amdgcn_mfma_f32_16x16x32_bf16(ah[rt], bl, acc[rt][ct], 0, 0, 0);
          acc[rt][ct] = __builtin_amdgcn_mfma_f32_16x16x32_bf16(al[rt], bh, acc[rt][ct], 0, 0, 0);
        }
      }
    }
  }

  // fused epilogue: y = acc + bias; t = y + x; x = LN(t)*g + b
  float gv[CT], bvv[CT], biasv[CT];
#pragma unroll
  for (int ct = 0; ct < CT; ct++) {
    int col = ct * 16 + l16;
    gv[ct] = g[col];
    bvv[ct] = b[col];
    biasv[ct] = bias[col];
  }
#pragma unroll
  for (int rt = 0; rt < 2; rt++) {
#pragma unroll
    for (int i = 0; i < 4; i++) {
      int r = row0 + rt * 16 + quad * 4 + i;
      int rl = min(r, nrows - 1);
      float t[CT];
      float s = 0.f;
#pragma unroll
      for (int ct = 0; ct < CT; ct++) {
        float yv = acc[rt][ct][i] + biasv[ct];
        if (STORE_Y && r < nrows) yout[(size_t)r * 128 + ct * 16 + l16] = yv;
        t[ct] = yv + x[(size_t)rl * 128 + ct * 16 + l16];
        s += t[ct];
      }
      s += __shfl_xor(s, 1); s += __shfl_xor(s, 2);
      s += __shfl_xor(s, 4); s += __shfl_xor(s, 8);
      float mean = s * (1.f / 128.f);
      float vv = 0.f;
#pragma unroll
      for (int ct = 0; ct < CT; ct++) {
        float d = t[ct] - mean;
        vv += d * d;
      }
      vv += __shfl_xor(vv, 1); vv += __shfl_xor(vv, 2);
      vv += __shfl_xor(vv, 4); vv += __shfl_xor(vv, 8);
      float inv = rsqrtf(vv * (1.f / 128.f) + 1e-5f);
      if (r < nrows) {
#pragma unroll
        for (int ct = 0; ct < CT; ct++)
          x[(size_t)r * 128 + ct * 16 + l16] = (t[ct] - mean) * inv * gv[ct] + bvv[ct];
      }
    }
  }
}

// ---------------- fused edge attention (bf16 qkv), one wave per dst node ----------------
__global__ __launch_bounds__(256) void attn_kernel(
    const unsigned short* __restrict__ qkv,
    const int* __restrict__ offsets, const int* __restrict__ csr,
    float* __restrict__ attn)
{
  int node = blockIdx.x * 4 + (threadIdx.x >> 6);
  int lane = threadIdx.x & 63;
  if (node >= N_NODES) return;
  float2 q2 = bf2f2(*(const unsigned int*)(qkv + (size_t)node * 384 + lane * 2));
  float wx = 0.f, wy = 0.f, z = 0.f;
  int j = offsets[node], end = offsets[node + 1];
  for (; j + 2 <= end; j += 2) {
    int s0 = csr[j], s1 = csr[j + 1];
    const unsigned short* r0 = qkv + (size_t)s0 * 384 + 128;
    const unsigned short* r1 = qkv + (size_t)s1 * 384 + 128;
    unsigned int ku0 = *(const unsigned int*)(r0 + lane * 2);
    unsigned int vu0 = *(const unsigned int*)(r0 + 128 + lane * 2);
    unsigned int ku1 = *(const unsigned int*)(r1 + lane * 2);
    unsigned int vu1 = *(const unsigned int*)(r1 + 128 + lane * 2);
    float2 ka = bf2f2(ku0), kb = bf2f2(ku1);
    float p0 = ka.x * q2.x + ka.y * q2.y;
    float p1 = kb.x * q2.x + kb.y * q2.y;
    p0 += __shfl_xor(p0, 1); p1 += __shfl_xor(p1, 1);
    p0 += __shfl_xor(p0, 2); p1 += __shfl_xor(p1, 2);
    p0 += __shfl_xor(p0, 4); p1 += __shfl_xor(p1, 4);
    float sc0 = __expf(fminf(fmaxf(p0 * 0.25f, -5.f), 5.f));
    float sc1 = __expf(fminf(fmaxf(p1 * 0.25f, -5.f), 5.f));
    float2 va = bf2f2(vu0), vb = bf2f2(vu1);
    wx = fmaf(sc0, va.x, wx); wy = fmaf(sc0, va.y, wy);
    wx = fmaf(sc1, vb.x, wx); wy = fmaf(sc1, vb.y, wy);
    z += sc0 + sc1;
  }
  if (j < end) {
    int s = csr[j];
    const unsigned short* r0 = qkv + (size_t)s * 384 + 128;
    float2 k2 = bf2f2(*(const unsigned int*)(r0 + lane * 2));
    float p = k2.x * q2.x + k2.y * q2.y;
    p += __shfl_xor(p, 1); p += __shfl_xor(p, 2); p += __shfl_xor(p, 4);
    float sc = __expf(fminf(fmaxf(p * 0.25f, -5.f), 5.f));
    float2 v2 = bf2f2(*(const unsigned int*)(r0 + 128 + lane * 2));
    wx = fmaf(sc, v2.x, wx); wy = fmaf(sc, v2.y, wy);
    z += sc;
  }
  float inv = 1.f / (z + 1e-6f);
  *(float2*)(attn + (size_t)node * DIM + lane * 2) = make_float2(wx * inv, wy * inv);
}

// ---------------- column mean over nodes ----------------
__global__ __launch_bounds__(256) void colmean_kernel(
    const float* __restrict__ x, float* __restrict__ mean)
{
  int col = threadIdx.x & 127;
  int half = threadIdx.x >> 7;
  float acc = 0.f;
  for (int r = blockIdx.x * 2 + half; r < N_NODES; r += gridDim.x * 2)
    acc += x[(size_t)r * DIM + col];
  __shared__ float s[256];
  s[threadIdx.x] = acc;
  __syncthreads();
  if (threadIdx.x < 128) atomicAdd(&mean[col], s[threadIdx.x] + s[threadIdx.x + 128]);
}

// ---------------- readout MLP 128->64->32->10 ----------------
__global__ void readout_kernel(
    const float* __restrict__ mean,
    const float* __restrict__ mW0, const float* __restrict__ mb0,
    const float* __restrict__ mW1, const float* __restrict__ mb1,
    const float* __restrict__ mW2, const float* __restrict__ mb2,
    float* __restrict__ out)
{
  __shared__ float sx[128], h0[64], h1[32];
  int t = threadIdx.x;
  sx[t] = mean[t] * (1.f / (float)N_NODES);
  __syncthreads();
  if (t < 64) {
    float a = mb0[t];
    for (int i = 0; i < 128; i++) a = fmaf(sx[i], mW0[i * 64 + t], a);
    h0[t] = fmaxf(a, 0.f);
  }
  __syncthreads();
  if (t < 32) {
    float a = mb1[t];
    for (int i = 0; i < 64; i++) a = fmaf(h0[i], mW1[i * 32 + t], a);
    h1[t] = fmaxf(a, 0.f);
  }
  __syncthreads();
  if (t < 10) {
    float a = mb2[t];
    for (int i = 0; i < 32; i++) a = fmaf(h1[i], mW2[i * 10 + t], a);
    out[t] = a;
  }
}

extern "C" void kernel_launch(void* const* d_in, const int* in_sizes, int n_in,
                              void* d_out, int out_size, void* d_ws, size_t ws_size,
                              hipStream_t stream) {
  const int*   x_idx = (const int*)d_in[0];
  const int*   eidx  = (const int*)d_in[1];
  const float* emb   = (const float*)d_in[2];
  const float* Wq = (const float*)d_in[3];  const float* bq = (const float*)d_in[4];
  const float* Wk = (const float*)d_in[5];  const float* bk = (const float*)d_in[6];
  const float* Wv = (const float*)d_in[7];  const float* bv = (const float*)d_in[8];
  const float* Wo = (const float*)d_in[9];  const float* bo = (const float*)d_in[10];
  const float* g1 = (const float*)d_in[11]; const float* be1 = (const float*)d_in[12];
  const float* Wf1 = (const float*)d_in[13]; const float* bf1 = (const float*)d_in[14];
  const float* Wf2 = (const float*)d_in[15]; const float* bf2 = (const float*)d_in[16];
  const float* g2 = (const float*)d_in[17]; const float* be2 = (const float*)d_in[18];
  const float* mW0 = (const float*)d_in[19]; const float* mb0 = (const float*)d_in[20];
  const float* mW1 = (const float*)d_in[21]; const float* mb1 = (const float*)d_in[22];
  const float* mW2 = (const float*)d_in[23]; const float* mb2 = (const float*)d_in[24];
  float* out = (float*)d_out;

  const size_t NX = (size_t)N_NODES * DIM;
  float* x = (float*)d_ws;
  float* shared_buf = x + NX;                 // 50000*256 floats: qkv(bf16) / ffh(fp32)
  float* a = shared_buf + (size_t)N_NODES * 256;
  float* y = a + NX;
  unsigned short* qkv = (unsigned short*)shared_buf;
  float* ffh = shared_buf;

  unsigned short* wqkv_p = (unsigned short*)(y + NX);          // 3*2*128*384
  unsigned short* wo_p   = wqkv_p + 3 * 2 * 128 * 384;         // 3*2*128*128
  unsigned short* wf1_p  = wo_p   + 3 * 2 * 128 * 128;         // 3*2*128*256
  unsigned short* wf2_p  = wf1_p  + 3 * 2 * 128 * 256;         // 3*2*256*128
  unsigned short* wend   = wf2_p  + 3 * 2 * 256 * 128;

  int* counts  = (int*)wend;
  int* offsets = counts + N_NODES;
  int* fill    = offsets + N_NODES + 1;
  int* bsums   = fill + N_NODES;
  int* csr     = bsums + 256;
  float* meanb = (float*)(csr + N_EDGES);

  const int* e0 = eidx;
  const int* e1 = eidx + N_EDGES;

  hipMemsetAsync(counts, 0, N_NODES * sizeof(int), stream);
  hipMemsetAsync(fill, 0, N_NODES * sizeof(int), stream);
  hipMemsetAsync(meanb, 0, DIM * sizeof(float), stream);

  prep_weights<<<24, 256, 0, stream>>>(Wq, wqkv_p, 128, 128, 384, 0, 3);
  prep_weights<<<24, 256, 0, stream>>>(Wk, wqkv_p, 128, 128, 384, 128, 3);
  prep_weights<<<24, 256, 0, stream>>>(Wv, wqkv_p, 128, 128, 384, 256, 3);
  prep_weights<<<24, 256, 0, stream>>>(Wo, wo_p, 128, 128, 128, 0, 3);
  prep_weights<<<48, 256, 0, stream>>>(Wf1, wf1_p, 128, 256, 256, 0, 3);
  prep_weights<<<48, 256, 0, stream>>>(Wf2, wf2_p, 256, 128, 128, 0, 3);

  embed_kernel<<<(N_NODES * 32 + 255) / 256, 256, 0, stream>>>(x_idx, emb, x);
  hist_kernel<<<(N_EDGES + 255) / 256, 256, 0, stream>>>(e1, counts);
  int nblk = (N_NODES + 255) / 256;
  scan_local<<<nblk, 256, 0, stream>>>(counts, offsets, bsums);
  scan_bsums<<<1, 256, 0, stream>>>(bsums, nblk);
  scan_add<<<nblk, 256, 0, stream>>>(offsets, bsums);
  scatter_kernel<<<(N_EDGES + 255) / 256, 256, 0, stream>>>(e0, e1, offsets, fill, csr);

  int gx = (N_NODES + 127) / 128;   // 391
  int nb4 = (N_NODES + 3) / 4;

  for (int l = 0; l < NLAYERS; ++l) {
    const unsigned short* wqkv_l = wqkv_p + (size_t)l * 2 * 128 * 384;
    const unsigned short* wo_l   = wo_p   + (size_t)l * 2 * 128 * 128;
    const unsigned short* wf1_l  = wf1_p  + (size_t)l * 2 * 128 * 256;
    const unsigned short* wf2_l  = wf2_p  + (size_t)l * 2 * 256 * 128;
    const float* bq_l = bq + (size_t)l * DIM;
    const float* bk_l = bk + (size_t)l * DIM;
    const float* bv_l = bv + (size_t)l * DIM;
    const float* bo_l = bo + (size_t)l * DIM;
    const float* bf1_l = bf1 + (size_t)l * 2 * DIM;
    const float* bf2_l = bf2 + (size_t)l * DIM;

    mfma_gemm_qkv<<<dim3(gx, 3), 256, 0, stream>>>(x, wqkv_l, bq_l, bk_l, bv_l, qkv, N_NODES);
    attn_kernel<<<nb4, 256, 0, stream>>>(qkv, offsets, csr, a);
    mfma_gemm_ln<128, true><<<dim3(gx, 1), 256, 0, stream>>>(
        a, wo_l, bo_l, x, y, g1 + (size_t)l * DIM, be1 + (size_t)l * DIM, N_NODES);
    mfma_gemm<128><<<dim3(gx, 2), 256, 0, stream>>>(y, wf1_l, 256, bf1_l, ffh, 256, N_NODES, 1);
    mfma_gemm_ln<256, false><<<dim3(gx, 1), 256, 0, stream>>>(
        ffh, wf2_l, bf2_l, x, nullptr, g2 + (size_t)l * DIM, be2 + (size_t)l * DIM, N_NODES);
  }

  colmean_kernel<<<128, 256, 0, stream>>>(x, meanb);
  readout_kernel<<<1, 128, 0, stream>>>(meanb, mW0, mb0, mW1, mb1, mW2, mb2, out);
}

// Round 4
// 817.775 us; speedup vs baseline: 2.4068x; 1.0648x over previous
//
#include <hip/hip_runtime.h>
#include <hip/hip_bf16.h>

#define N_NODES 50000
#define N_EDGES 800000
#define DIM 128
#define NLAYERS 3

typedef short bf16x8 __attribute__((ext_vector_type(8)));
typedef float floatx4 __attribute__((ext_vector_type(4)));

__device__ __forceinline__ unsigned short f2bf(float f) {
  unsigned int u = __builtin_bit_cast(unsigned int, f);
  return (unsigned short)((u + 0x7FFFu + ((u >> 16) & 1u)) >> 16);
}
__device__ __forceinline__ float bfhi(float f, unsigned short& hb) {
  unsigned int u = __builtin_bit_cast(unsigned int, f);
  unsigned int r = (u + 0x7FFFu + ((u >> 16) & 1u)) & 0xFFFF0000u;
  hb = (unsigned short)(r >> 16);
  return __builtin_bit_cast(float, r);
}
__device__ __forceinline__ float2 bf2f2(unsigned int u) {
  float lo = __builtin_bit_cast(float, u << 16);
  float hi = __builtin_bit_cast(float, u & 0xFFFF0000u);
  return make_float2(lo, hi);
}

// ---------------- embedding gather: x fp32 + xb bf16 ----------------
__global__ __launch_bounds__(256) void embed_kernel(
    const int* __restrict__ idx, const float* __restrict__ emb,
    float* __restrict__ x, unsigned short* __restrict__ xb)
{
  int gid = blockIdx.x * 256 + threadIdx.x;
  int n = gid >> 5;
  int c = (gid & 31) << 2;
  if (n >= N_NODES) return;
  int e = idx[n];
  float4 val = *(const float4*)(emb + (size_t)e * DIM + c);
  *(float4*)(x + (size_t)n * DIM + c) = val;
  ushort4 pk;
  pk.x = f2bf(val.x); pk.y = f2bf(val.y); pk.z = f2bf(val.z); pk.w = f2bf(val.w);
  *(ushort4*)(xb + (size_t)n * DIM + c) = pk;
}

// ---------------- CSR build ----------------
__global__ __launch_bounds__(256) void hist_kernel(
    const int* __restrict__ e1, int* __restrict__ counts)
{
  int i = blockIdx.x * 256 + threadIdx.x;
  if (i < N_EDGES) atomicAdd(&counts[e1[i]], 1);
}

__global__ __launch_bounds__(256) void scan_local(
    const int* __restrict__ counts, int* __restrict__ offsets,
    int* __restrict__ bsums)
{
  __shared__ int buf[256];
  int t = threadIdx.x;
  int i = blockIdx.x * 256 + t;
  int v = (i < N_NODES) ? counts[i] : 0;
  buf[t] = v;
  __syncthreads();
  int s = v;
#pragma unroll
  for (int off = 1; off < 256; off <<= 1) {
    int t2 = (t >= off) ? buf[t - off] : 0;
    __syncthreads();
    s += t2;
    buf[t] = s;
    __syncthreads();
  }
  if (i < N_NODES) offsets[i] = s - v;
  if (t == 255) bsums[blockIdx.x] = s;
}

__global__ void scan_bsums(int* __restrict__ bsums, int nblk)
{
  __shared__ int buf[256];
  int t = threadIdx.x;
  int v = (t < nblk) ? bsums[t] : 0;
  buf[t] = v;
  __syncthreads();
  int s = v;
#pragma unroll
  for (int off = 1; off < 256; off <<= 1) {
    int t2 = (t >= off) ? buf[t - off] : 0;
    __syncthreads();
    s += t2;
    buf[t] = s;
    __syncthreads();
  }
  if (t < nblk) bsums[t] = s - v;
}

__global__ __launch_bounds__(256) void scan_add(
    int* __restrict__ offsets, const int* __restrict__ bsums)
{
  int i = blockIdx.x * 256 + threadIdx.x;
  if (i < N_NODES) offsets[i] += bsums[blockIdx.x];
  if (i == 0) offsets[N_NODES] = N_EDGES;
}

__global__ __launch_bounds__(256) void scatter_kernel(
    const int* __restrict__ e0, const int* __restrict__ e1,
    const int* __restrict__ offsets, int* __restrict__ fill,
    int* __restrict__ csr)
{
  int i = blockIdx.x * 256 + threadIdx.x;
  if (i >= N_EDGES) return;
  int d = e1[i];
  int pos = offsets[d] + atomicAdd(&fill[d], 1);
  csr[pos] = e0[i];
}

// ---------------- weight prep ----------------
// hi/lo two-plane frag-major (planes: hi at 0, lo at +K*Ndst ushorts)
__global__ __launch_bounds__(256) void prep_weights2(
    const float* __restrict__ W, unsigned short* __restrict__ out,
    int K, int Nsrc, int Ndst, int c0, int L)
{
  int g = blockIdx.x * 256 + threadIdx.x;
  int fragsPerMat = (K / 8) * Nsrc;
  int total = L * fragsPerMat;
  if (g >= total) return;
  int l = g / fragsPerMat;
  int rem = g - l * fragsPerMat;
  int kq = rem / Nsrc;
  int n = rem - kq * Nsrc;
  const float* Wl = W + (size_t)l * K * Nsrc;
  unsigned short* basehi = out + (size_t)l * 2 * K * Ndst + (size_t)(kq * Ndst + c0 + n) * 8;
  unsigned short* baselo = basehi + (size_t)K * Ndst;
#pragma unroll
  for (int j = 0; j < 8; j++) {
    float f = Wl[(size_t)(kq * 8 + j) * Nsrc + n];
    unsigned short hb;
    float hf = bfhi(f, hb);
    basehi[j] = hb;
    baselo[j] = f2bf(f - hf);
  }
}

// single-plane frag-major (plain bf16 round)
__global__ __launch_bounds__(256) void prep_weights1(
    const float* __restrict__ W, unsigned short* __restrict__ out,
    int K, int Nsrc, int Ndst, int c0, int L)
{
  int g = blockIdx.x * 256 + threadIdx.x;
  int fragsPerMat = (K / 8) * Nsrc;
  int total = L * fragsPerMat;
  if (g >= total) return;
  int l = g / fragsPerMat;
  int rem = g - l * fragsPerMat;
  int kq = rem / Nsrc;
  int n = rem - kq * Nsrc;
  const float* Wl = W + (size_t)l * K * Nsrc;
  unsigned short* base = out + (size_t)l * K * Ndst + (size_t)(kq * Ndst + c0 + n) * 8;
#pragma unroll
  for (int j = 0; j < 8; j++)
    base[j] = f2bf(Wl[(size_t)(kq * 8 + j) * Nsrc + n]);
}

// ---------------- QKV GEMM: bf16 A, single-plane W, bf16 out ----------------
__global__ __launch_bounds__(256) void mfma_gemm_qkv(
    const unsigned short* __restrict__ Ab,
    const unsigned short* __restrict__ Wp,
    const float* __restrict__ bq, const float* __restrict__ bk,
    const float* __restrict__ bv,
    unsigned short* __restrict__ out, int nrows)
{
  constexpr int K = 128, N = 384, CT = 8;
  __shared__ unsigned short SW[16 * 128 * 8];   // 32 KB (hi only)
  int tid = threadIdx.x;
  int c0 = blockIdx.y * 128;
  const float* bias = (blockIdx.y == 0) ? bq : (blockIdx.y == 1) ? bk : bv;
  int wave = tid >> 6, lane = tid & 63;
  int quad = lane >> 4, l16 = lane & 15;
  int row0 = blockIdx.x * 128 + wave * 32;

  floatx4 acc[2][CT];
#pragma unroll
  for (int rt = 0; rt < 2; rt++)
#pragma unroll
    for (int ct = 0; ct < CT; ct++) acc[rt][ct] = (floatx4)(0.f);

  const unsigned short* arow[2];
#pragma unroll
  for (int rt = 0; rt < 2; rt++) {
    int r = min(row0 + rt * 16 + l16, nrows - 1);
    arow[rt] = Ab + (size_t)r * K + quad * 8;
  }
#pragma unroll 4
  for (int f = tid; f < 16 * 128; f += 256) {
    int kq = f >> 7;
    int n = f & 127;
    *(bf16x8*)&SW[f * 8] = *(const bf16x8*)&Wp[(size_t)(kq * N + c0 + n) * 8];
  }
  __syncthreads();
#pragma unroll
  for (int kb = 0; kb < 4; ++kb) {
    bf16x8 av[2];
#pragma unroll
    for (int rt = 0; rt < 2; rt++)
      av[rt] = *(const bf16x8*)(arow[rt] + kb * 32);
#pragma unroll
    for (int ct = 0; ct < CT; ct++) {
      bf16x8 bh = *(bf16x8*)&SW[((kb * 4 + quad) * 128 + ct * 16 + l16) * 8];
#pragma unroll
      for (int rt = 0; rt < 2; rt++)
        acc[rt][ct] = __builtin_amdgcn_mfma_f32_16x16x32_bf16(av[rt], bh, acc[rt][ct], 0, 0, 0);
    }
  }
#pragma unroll
  for (int ct = 0; ct < CT; ct++) {
    float bvv = bias[ct * 16 + l16];
    int col = c0 + ct * 16 + l16;
#pragma unroll
    for (int rt = 0; rt < 2; rt++)
#pragma unroll
      for (int i = 0; i < 4; i++) {
        int r = row0 + rt * 16 + quad * 4 + i;
        if (r < nrows)
          out[(size_t)r * 384 + col] = f2bf(acc[rt][ct][i] + bvv);
      }
  }
}

// ---------------- FFN1 GEMM: bf16 A, hi/lo W (2 MFMA), relu, bf16 out (N=256) ----------------
__global__ __launch_bounds__(256) void mfma_gemm_ffn1(
    const unsigned short* __restrict__ Ab,
    const unsigned short* __restrict__ Wp,
    const float* __restrict__ bias,
    unsigned short* __restrict__ out, int nrows)
{
  constexpr int K = 128, N = 256, CT = 8;
  __shared__ unsigned short SW[2 * 16 * 128 * 8];  // 64 KB
  int tid = threadIdx.x;
  int c0 = blockIdx.y * 128;
  int wave = tid >> 6, lane = tid & 63;
  int quad = lane >> 4, l16 = lane & 15;
  int row0 = blockIdx.x * 128 + wave * 32;

  floatx4 acc[2][CT];
#pragma unroll
  for (int rt = 0; rt < 2; rt++)
#pragma unroll
    for (int ct = 0; ct < CT; ct++) acc[rt][ct] = (floatx4)(0.f);

  const unsigned short* arow[2];
#pragma unroll
  for (int rt = 0; rt < 2; rt++) {
    int r = min(row0 + rt * 16 + l16, nrows - 1);
    arow[rt] = Ab + (size_t)r * K + quad * 8;
  }
  const int planeStride = K * N;
#pragma unroll 4
  for (int f = tid; f < 2 * 16 * 128; f += 256) {
    int p = f >> 11;
    int rem = f & 2047;
    int kq = rem >> 7;
    int n = rem & 127;
    *(bf16x8*)&SW[f * 8] =
        *(const bf16x8*)&Wp[(size_t)p * planeStride + (size_t)(kq * N + c0 + n) * 8];
  }
  __syncthreads();
#pragma unroll
  for (int kb = 0; kb < 4; ++kb) {
    bf16x8 av[2];
#pragma unroll
    for (int rt = 0; rt < 2; rt++)
      av[rt] = *(const bf16x8*)(arow[rt] + kb * 32);
#pragma unroll
    for (int ct = 0; ct < CT; ct++) {
      int base = ((kb * 4 + quad) * 128 + ct * 16 + l16) * 8;
      bf16x8 bh = *(bf16x8*)&SW[base];
      bf16x8 bl = *(bf16x8*)&SW[16 * 128 * 8 + base];
#pragma unroll
      for (int rt = 0; rt < 2; rt++) {
        acc[rt][ct] = __builtin_amdgcn_mfma_f32_16x16x32_bf16(av[rt], bh, acc[rt][ct], 0, 0, 0);
        acc[rt][ct] = __builtin_amdgcn_mfma_f32_16x16x32_bf16(av[rt], bl, acc[rt][ct], 0, 0, 0);
      }
    }
  }
#pragma unroll
  for (int ct = 0; ct < CT; ct++) {
    int col = c0 + ct * 16 + l16;
    float bvv = bias[col];
#pragma unroll
    for (int rt = 0; rt < 2; rt++)
#pragma unroll
      for (int i = 0; i < 4; i++) {
        int r = row0 + rt * 16 + quad * 4 + i;
        if (r < nrows)
          out[(size_t)r * 256 + col] = f2bf(fmaxf(acc[rt][ct][i] + bvv, 0.f));
      }
  }
}

// ---------------- GEMM + fused residual LN: bf16 A, hi/lo W (2 MFMA) ----------------
// y = A@W + bias; if STORE_Y: yout(bf16) = y;  x = LN(x + y)*g + b (x fp32, xb bf16)
template<int K, bool STORE_Y>
__global__ __launch_bounds__(256) void mfma_gemm_ln(
    const unsigned short* __restrict__ Ab,
    const unsigned short* __restrict__ Wp,
    const float* __restrict__ bias,
    float* __restrict__ x, unsigned short* __restrict__ xb,
    unsigned short* __restrict__ yout,
    const float* __restrict__ g, const float* __restrict__ b, int nrows)
{
  constexpr int N = 128, CT = 8;
  __shared__ unsigned short SW[2 * 16 * 128 * 8];  // 64 KB chunk
  int tid = threadIdx.x;
  int wave = tid >> 6, lane = tid & 63;
  int quad = lane >> 4, l16 = lane & 15;
  int row0 = blockIdx.x * 128 + wave * 32;

  floatx4 acc[2][CT];
#pragma unroll
  for (int rt = 0; rt < 2; rt++)
#pragma unroll
    for (int ct = 0; ct < CT; ct++) acc[rt][ct] = (floatx4)(0.f);

  const unsigned short* arow[2];
#pragma unroll
  for (int rt = 0; rt < 2; rt++) {
    int r = min(row0 + rt * 16 + l16, nrows - 1);
    arow[rt] = Ab + (size_t)r * K + quad * 8;
  }
  const int planeStride = K * N;

  for (int kc0 = 0; kc0 < K; kc0 += 128) {
    __syncthreads();
#pragma unroll 4
    for (int f = tid; f < 2 * 16 * 128; f += 256) {
      int p = f >> 11;
      int rem = f & 2047;
      int kq = rem >> 7;
      int n = rem & 127;
      *(bf16x8*)&SW[f * 8] =
          *(const bf16x8*)&Wp[(size_t)p * planeStride +
                              (size_t)((kc0 / 8 + kq) * N + n) * 8];
    }
    __syncthreads();
#pragma unroll
    for (int kb = 0; kb < 4; ++kb) {
      bf16x8 av[2];
#pragma unroll
      for (int rt = 0; rt < 2; rt++)
        av[rt] = *(const bf16x8*)(arow[rt] + kc0 + kb * 32);
#pragma unroll
      for (int ct = 0; ct < CT; ct++) {
        int base = ((kb * 4 + quad) * 128 + ct * 16 + l16) * 8;
        bf16x8 bh = *(bf16x8*)&SW[base];
        bf16x8 bl = *(bf16x8*)&SW[16 * 128 * 8 + base];
#pragma unroll
        for (int rt = 0; rt < 2; rt++) {
          acc[rt][ct] = __builtin_amdgcn_mfma_f32_16x16x32_bf16(av[rt], bh, acc[rt][ct], 0, 0, 0);
          acc[rt][ct] = __builtin_amdgcn_mfma_f32_16x16x32_bf16(av[rt], bl, acc[rt][ct], 0, 0, 0);
        }
      }
    }
  }

  float gv[CT], bvv[CT], biasv[CT];
#pragma unroll
  for (int ct = 0; ct < CT; ct++) {
    int col = ct * 16 + l16;
    gv[ct] = g[col];
    bvv[ct] = b[col];
    biasv[ct] = bias[col];
  }
#pragma unroll
  for (int rt = 0; rt < 2; rt++) {
#pragma unroll
    for (int i = 0; i < 4; i++) {
      int r = row0 + rt * 16 + quad * 4 + i;
      int rl = min(r, nrows - 1);
      float t[CT];
      float s = 0.f;
#pragma unroll
      for (int ct = 0; ct < CT; ct++) {
        float yv = acc[rt][ct][i] + biasv[ct];
        if (STORE_Y && r < nrows) yout[(size_t)r * 128 + ct * 16 + l16] = f2bf(yv);
        t[ct] = yv + x[(size_t)rl * 128 + ct * 16 + l16];
        s += t[ct];
      }
      s += __shfl_xor(s, 1); s += __shfl_xor(s, 2);
      s += __shfl_xor(s, 4); s += __shfl_xor(s, 8);
      float mean = s * (1.f / 128.f);
      float vv = 0.f;
#pragma unroll
      for (int ct = 0; ct < CT; ct++) {
        float d = t[ct] - mean;
        vv += d * d;
      }
      vv += __shfl_xor(vv, 1); vv += __shfl_xor(vv, 2);
      vv += __shfl_xor(vv, 4); vv += __shfl_xor(vv, 8);
      float inv = rsqrtf(vv * (1.f / 128.f) + 1e-5f);
      if (r < nrows) {
#pragma unroll
        for (int ct = 0; ct < CT; ct++) {
          float o = (t[ct] - mean) * inv * gv[ct] + bvv[ct];
          x[(size_t)r * 128 + ct * 16 + l16] = o;
          xb[(size_t)r * 128 + ct * 16 + l16] = f2bf(o);
        }
      }
    }
  }
}

// ---------------- fused edge attention (bf16 qkv), one wave per dst node ----------------
__global__ __launch_bounds__(256) void attn_kernel(
    const unsigned short* __restrict__ qkv,
    const int* __restrict__ offsets, const int* __restrict__ csr,
    unsigned short* __restrict__ attn)
{
  int node = blockIdx.x * 4 + (threadIdx.x >> 6);
  int lane = threadIdx.x & 63;
  if (node >= N_NODES) return;
  float2 q2 = bf2f2(*(const unsigned int*)(qkv + (size_t)node * 384 + lane * 2));
  float wx = 0.f, wy = 0.f, z = 0.f;
  int j = offsets[node], end = offsets[node + 1];
  for (; j + 2 <= end; j += 2) {
    int s0 = csr[j], s1 = csr[j + 1];
    const unsigned short* r0 = qkv + (size_t)s0 * 384 + 128;
    const unsigned short* r1 = qkv + (size_t)s1 * 384 + 128;
    unsigned int ku0 = *(const unsigned int*)(r0 + lane * 2);
    unsigned int vu0 = *(const unsigned int*)(r0 + 128 + lane * 2);
    unsigned int ku1 = *(const unsigned int*)(r1 + lane * 2);
    unsigned int vu1 = *(const unsigned int*)(r1 + 128 + lane * 2);
    float2 ka = bf2f2(ku0), kb = bf2f2(ku1);
    float p0 = ka.x * q2.x + ka.y * q2.y;
    float p1 = kb.x * q2.x + kb.y * q2.y;
    p0 += __shfl_xor(p0, 1); p1 += __shfl_xor(p1, 1);
    p0 += __shfl_xor(p0, 2); p1 += __shfl_xor(p1, 2);
    p0 += __shfl_xor(p0, 4); p1 += __shfl_xor(p1, 4);
    float sc0 = __expf(fminf(fmaxf(p0 * 0.25f, -5.f), 5.f));
    float sc1 = __expf(fminf(fmaxf(p1 * 0.25f, -5.f), 5.f));
    float2 va = bf2f2(vu0), vb = bf2f2(vu1);
    wx = fmaf(sc0, va.x, wx); wy = fmaf(sc0, va.y, wy);
    wx = fmaf(sc1, vb.x, wx); wy = fmaf(sc1, vb.y, wy);
    z += sc0 + sc1;
  }
  if (j < end) {
    int s = csr[j];
    const unsigned short* r0 = qkv + (size_t)s * 384 + 128;
    float2 k2 = bf2f2(*(const unsigned int*)(r0 + lane * 2));
    float p = k2.x * q2.x + k2.y * q2.y;
    p += __shfl_xor(p, 1); p += __shfl_xor(p, 2); p += __shfl_xor(p, 4);
    float sc = __expf(fminf(fmaxf(p * 0.25f, -5.f), 5.f));
    float2 v2 = bf2f2(*(const unsigned int*)(r0 + 128 + lane * 2));
    wx = fmaf(sc, v2.x, wx); wy = fmaf(sc, v2.y, wy);
    z += sc;
  }
  float inv = 1.f / (z + 1e-6f);
  unsigned int pack = (unsigned int)f2bf(wx * inv) | ((unsigned int)f2bf(wy * inv) << 16);
  *(unsigned int*)(attn + (size_t)node * DIM + lane * 2) = pack;
}

// ---------------- column mean over nodes ----------------
__global__ __launch_bounds__(256) void colmean_kernel(
    const float* __restrict__ x, float* __restrict__ mean)
{
  int col = threadIdx.x & 127;
  int half = threadIdx.x >> 7;
  float acc = 0.f;
  for (int r = blockIdx.x * 2 + half; r < N_NODES; r += gridDim.x * 2)
    acc += x[(size_t)r * DIM + col];
  __shared__ float s[256];
  s[threadIdx.x] = acc;
  __syncthreads();
  if (threadIdx.x < 128) atomicAdd(&mean[col], s[threadIdx.x] + s[threadIdx.x + 128]);
}

// ---------------- readout MLP 128->64->32->10 ----------------
__global__ void readout_kernel(
    const float* __restrict__ mean,
    const float* __restrict__ mW0, const float* __restrict__ mb0,
    const float* __restrict__ mW1, const float* __restrict__ mb1,
    const float* __restrict__ mW2, const float* __restrict__ mb2,
    float* __restrict__ out)
{
  __shared__ float sx[128], h0[64], h1[32];
  int t = threadIdx.x;
  sx[t] = mean[t] * (1.f / (float)N_NODES);
  __syncthreads();
  if (t < 64) {
    float a = mb0[t];
    for (int i = 0; i < 128; i++) a = fmaf(sx[i], mW0[i * 64 + t], a);
    h0[t] = fmaxf(a, 0.f);
  }
  __syncthreads();
  if (t < 32) {
    float a = mb1[t];
    for (int i = 0; i < 64; i++) a = fmaf(h0[i], mW1[i * 32 + t], a);
    h1[t] = fmaxf(a, 0.f);
  }
  __syncthreads();
  if (t < 10) {
    float a = mb2[t];
    for (int i = 0; i < 32; i++) a = fmaf(h1[i], mW2[i * 10 + t], a);
    out[t] = a;
  }
}

extern "C" void kernel_launch(void* const* d_in, const int* in_sizes, int n_in,
                              void* d_out, int out_size, void* d_ws, size_t ws_size,
                              hipStream_t stream) {
  const int*   x_idx = (const int*)d_in[0];
  const int*   eidx  = (const int*)d_in[1];
  const float* emb   = (const float*)d_in[2];
  const float* Wq = (const float*)d_in[3];  const float* bq = (const float*)d_in[4];
  const float* Wk = (const float*)d_in[5];  const float* bk = (const float*)d_in[6];
  const float* Wv = (const float*)d_in[7];  const float* bv = (const float*)d_in[8];
  const float* Wo = (const float*)d_in[9];  const float* bo = (const float*)d_in[10];
  const float* g1 = (const float*)d_in[11]; const float* be1 = (const float*)d_in[12];
  const float* Wf1 = (const float*)d_in[13]; const float* bf1 = (const float*)d_in[14];
  const float* Wf2 = (const float*)d_in[15]; const float* bf2 = (const float*)d_in[16];
  const float* g2 = (const float*)d_in[17]; const float* be2 = (const float*)d_in[18];
  const float* mW0 = (const float*)d_in[19]; const float* mb0 = (const float*)d_in[20];
  const float* mW1 = (const float*)d_in[21]; const float* mb1 = (const float*)d_in[22];
  const float* mW2 = (const float*)d_in[23]; const float* mb2 = (const float*)d_in[24];
  float* out = (float*)d_out;

  const size_t NX = (size_t)N_NODES * DIM;
  float* x = (float*)d_ws;                                    // fp32 residual
  unsigned short* xb  = (unsigned short*)(x + NX);            // bf16 residual
  unsigned short* qkv = xb + NX;                              // [N,384] bf16
  unsigned short* a   = qkv + (size_t)N_NODES * 384;          // attn out bf16
  unsigned short* y   = a + NX;                               // attn proj bf16
  unsigned short* ffh = y + NX;                               // [N,256] bf16

  unsigned short* wqkv_p = ffh + (size_t)N_NODES * 256;       // 3*128*384 (single)
  unsigned short* wo_p   = wqkv_p + 3 * 128 * 384;            // 3*2*128*128
  unsigned short* wf1_p  = wo_p   + 3 * 2 * 128 * 128;        // 3*2*128*256
  unsigned short* wf2_p  = wf1_p  + 3 * 2 * 128 * 256;        // 3*2*256*128
  unsigned short* wend   = wf2_p  + 3 * 2 * 256 * 128;

  int* counts  = (int*)wend;
  int* offsets = counts + N_NODES;
  int* fill    = offsets + N_NODES + 1;
  int* bsums   = fill + N_NODES;
  int* csr     = bsums + 256;
  float* meanb = (float*)(csr + N_EDGES);

  const int* e0 = eidx;
  const int* e1 = eidx + N_EDGES;

  hipMemsetAsync(counts, 0, N_NODES * sizeof(int), stream);
  hipMemsetAsync(fill, 0, N_NODES * sizeof(int), stream);
  hipMemsetAsync(meanb, 0, DIM * sizeof(float), stream);

  prep_weights1<<<24, 256, 0, stream>>>(Wq, wqkv_p, 128, 128, 384, 0, 3);
  prep_weights1<<<24, 256, 0, stream>>>(Wk, wqkv_p, 128, 128, 384, 128, 3);
  prep_weights1<<<24, 256, 0, stream>>>(Wv, wqkv_p, 128, 128, 384, 256, 3);
  prep_weights2<<<24, 256, 0, stream>>>(Wo, wo_p, 128, 128, 128, 0, 3);
  prep_weights2<<<48, 256, 0, stream>>>(Wf1, wf1_p, 128, 256, 256, 0, 3);
  prep_weights2<<<48, 256, 0, stream>>>(Wf2, wf2_p, 256, 128, 128, 0, 3);

  embed_kernel<<<(N_NODES * 32 + 255) / 256, 256, 0, stream>>>(x_idx, emb, x, xb);
  hist_kernel<<<(N_EDGES + 255) / 256, 256, 0, stream>>>(e1, counts);
  int nblk = (N_NODES + 255) / 256;
  scan_local<<<nblk, 256, 0, stream>>>(counts, offsets, bsums);
  scan_bsums<<<1, 256, 0, stream>>>(bsums, nblk);
  scan_add<<<nblk, 256, 0, stream>>>(offsets, bsums);
  scatter_kernel<<<(N_EDGES + 255) / 256, 256, 0, stream>>>(e0, e1, offsets, fill, csr);

  int gx = (N_NODES + 127) / 128;   // 391
  int nb4 = (N_NODES + 3) / 4;

  for (int l = 0; l < NLAYERS; ++l) {
    const unsigned short* wqkv_l = wqkv_p + (size_t)l * 128 * 384;
    const unsigned short* wo_l   = wo_p   + (size_t)l * 2 * 128 * 128;
    const unsigned short* wf1_l  = wf1_p  + (size_t)l * 2 * 128 * 256;
    const unsigned short* wf2_l  = wf2_p  + (size_t)l * 2 * 256 * 128;
    const float* bq_l = bq + (size_t)l * DIM;
    const float* bk_l = bk + (size_t)l * DIM;
    const float* bv_l = bv + (size_t)l * DIM;
    const float* bo_l = bo + (size_t)l * DIM;
    const float* bf1_l = bf1 + (size_t)l * 2 * DIM;
    const float* bf2_l = bf2 + (size_t)l * DIM;

    mfma_gemm_qkv<<<dim3(gx, 3), 256, 0, stream>>>(xb, wqkv_l, bq_l, bk_l, bv_l, qkv, N_NODES);
    attn_kernel<<<nb4, 256, 0, stream>>>(qkv, offsets, csr, a);
    mfma_gemm_ln<128, true><<<dim3(gx, 1), 256, 0, stream>>>(
        a, wo_l, bo_l, x, xb, y, g1 + (size_t)l * DIM, be1 + (size_t)l * DIM, N_NODES);
    mfma_gemm_ffn1<<<dim3(gx, 2), 256, 0, stream>>>(y, wf1_l, bf1_l, ffh, N_NODES);
    mfma_gemm_ln<256, false><<<dim3(gx, 1), 256, 0, stream>>>(
        ffh, wf2_l, bf2_l, x, xb, nullptr, g2 + (size_t)l * DIM, be2 + (size_t)l * DIM, N_NODES);
  }

  colmean_kernel<<<128, 256, 0, stream>>>(x, meanb);
  readout_kernel<<<1, 128, 0, stream>>>(meanb, mW0, mb0, mW1, mb1, mW2, mb2, out);
}

// Round 5
// 742.457 us; speedup vs baseline: 2.6510x; 1.1014x over previous
//
#include <hip/hip_runtime.h>
#include <hip/hip_bf16.h>

#define N_NODES 50000
#define N_EDGES 800000
#define DIM 128
#define NLAYERS 3

typedef short bf16x8 __attribute__((ext_vector_type(8)));
typedef float floatx4 __attribute__((ext_vector_type(4)));

__device__ __forceinline__ unsigned short f2bf(float f) {
  unsigned int u = __builtin_bit_cast(unsigned int, f);
  return (unsigned short)((u + 0x7FFFu + ((u >> 16) & 1u)) >> 16);
}
__device__ __forceinline__ float bf2f(unsigned short h) {
  return __builtin_bit_cast(float, (unsigned int)h << 16);
}
__device__ __forceinline__ float bfhi(float f, unsigned short& hb) {
  unsigned int u = __builtin_bit_cast(unsigned int, f);
  unsigned int r = (u + 0x7FFFu + ((u >> 16) & 1u)) & 0xFFFF0000u;
  hb = (unsigned short)(r >> 16);
  return __builtin_bit_cast(float, r);
}
__device__ __forceinline__ float2 bf2f2(unsigned int u) {
  float lo = __builtin_bit_cast(float, u << 16);
  float hi = __builtin_bit_cast(float, u & 0xFFFF0000u);
  return make_float2(lo, hi);
}

// ---------------- embedding gather -> bf16 residual ----------------
__global__ __launch_bounds__(256) void embed_kernel(
    const int* __restrict__ idx, const float* __restrict__ emb,
    unsigned short* __restrict__ xb)
{
  int gid = blockIdx.x * 256 + threadIdx.x;
  int n = gid >> 5;
  int c = (gid & 31) << 2;
  if (n >= N_NODES) return;
  int e = idx[n];
  float4 val = *(const float4*)(emb + (size_t)e * DIM + c);
  ushort4 pk;
  pk.x = f2bf(val.x); pk.y = f2bf(val.y); pk.z = f2bf(val.z); pk.w = f2bf(val.w);
  *(ushort4*)(xb + (size_t)n * DIM + c) = pk;
}

// ---------------- CSR build ----------------
__global__ __launch_bounds__(256) void hist_kernel(
    const int* __restrict__ e1, int* __restrict__ counts)
{
  int i = blockIdx.x * 256 + threadIdx.x;
  if (i < N_EDGES) atomicAdd(&counts[e1[i]], 1);
}

__global__ __launch_bounds__(256) void scan_local(
    const int* __restrict__ counts, int* __restrict__ offsets,
    int* __restrict__ bsums)
{
  __shared__ int buf[256];
  int t = threadIdx.x;
  int i = blockIdx.x * 256 + t;
  int v = (i < N_NODES) ? counts[i] : 0;
  buf[t] = v;
  __syncthreads();
  int s = v;
#pragma unroll
  for (int off = 1; off < 256; off <<= 1) {
    int t2 = (t >= off) ? buf[t - off] : 0;
    __syncthreads();
    s += t2;
    buf[t] = s;
    __syncthreads();
  }
  if (i < N_NODES) offsets[i] = s - v;
  if (t == 255) bsums[blockIdx.x] = s;
}

__global__ void scan_bsums(int* __restrict__ bsums, int nblk)
{
  __shared__ int buf[256];
  int t = threadIdx.x;
  int v = (t < nblk) ? bsums[t] : 0;
  buf[t] = v;
  __syncthreads();
  int s = v;
#pragma unroll
  for (int off = 1; off < 256; off <<= 1) {
    int t2 = (t >= off) ? buf[t - off] : 0;
    __syncthreads();
    s += t2;
    buf[t] = s;
    __syncthreads();
  }
  if (t < nblk) bsums[t] = s - v;
}

__global__ __launch_bounds__(256) void scan_add(
    int* __restrict__ offsets, const int* __restrict__ bsums)
{
  int i = blockIdx.x * 256 + threadIdx.x;
  if (i < N_NODES) offsets[i] += bsums[blockIdx.x];
  if (i == 0) offsets[N_NODES] = N_EDGES;
}

__global__ __launch_bounds__(256) void scatter_kernel(
    const int* __restrict__ e0, const int* __restrict__ e1,
    const int* __restrict__ offsets, int* __restrict__ fill,
    int* __restrict__ csr)
{
  int i = blockIdx.x * 256 + threadIdx.x;
  if (i >= N_EDGES) return;
  int d = e1[i];
  int pos = offsets[d] + atomicAdd(&fill[d], 1);
  csr[pos] = e0[i];
}

// ---------------- weight prep ----------------
__global__ __launch_bounds__(256) void prep_weights2(
    const float* __restrict__ W, unsigned short* __restrict__ out,
    int K, int Nsrc, int Ndst, int c0, int L)
{
  int g = blockIdx.x * 256 + threadIdx.x;
  int fragsPerMat = (K / 8) * Nsrc;
  int total = L * fragsPerMat;
  if (g >= total) return;
  int l = g / fragsPerMat;
  int rem = g - l * fragsPerMat;
  int kq = rem / Nsrc;
  int n = rem - kq * Nsrc;
  const float* Wl = W + (size_t)l * K * Nsrc;
  unsigned short* basehi = out + (size_t)l * 2 * K * Ndst + (size_t)(kq * Ndst + c0 + n) * 8;
  unsigned short* baselo = basehi + (size_t)K * Ndst;
#pragma unroll
  for (int j = 0; j < 8; j++) {
    float f = Wl[(size_t)(kq * 8 + j) * Nsrc + n];
    unsigned short hb;
    float hf = bfhi(f, hb);
    basehi[j] = hb;
    baselo[j] = f2bf(f - hf);
  }
}

__global__ __launch_bounds__(256) void prep_weights1(
    const float* __restrict__ W, unsigned short* __restrict__ out,
    int K, int Nsrc, int Ndst, int c0, int L)
{
  int g = blockIdx.x * 256 + threadIdx.x;
  int fragsPerMat = (K / 8) * Nsrc;
  int total = L * fragsPerMat;
  if (g >= total) return;
  int l = g / fragsPerMat;
  int rem = g - l * fragsPerMat;
  int kq = rem / Nsrc;
  int n = rem - kq * Nsrc;
  const float* Wl = W + (size_t)l * K * Nsrc;
  unsigned short* base = out + (size_t)l * K * Ndst + (size_t)(kq * Ndst + c0 + n) * 8;
#pragma unroll
  for (int j = 0; j < 8; j++)
    base[j] = f2bf(Wl[(size_t)(kq * 8 + j) * Nsrc + n]);
}

// ---------------- QKV GEMM: bf16 A, single-plane W, bf16 out ----------------
__global__ __launch_bounds__(256) void mfma_gemm_qkv(
    const unsigned short* __restrict__ Ab,
    const unsigned short* __restrict__ Wp,
    const float* __restrict__ bq, const float* __restrict__ bk,
    const float* __restrict__ bv,
    unsigned short* __restrict__ out, int nrows)
{
  constexpr int K = 128, N = 384, CT = 8;
  __shared__ unsigned short SW[16 * 128 * 8];   // 32 KB
  int tid = threadIdx.x;
  int c0 = blockIdx.y * 128;
  const float* bias = (blockIdx.y == 0) ? bq : (blockIdx.y == 1) ? bk : bv;
  int wave = tid >> 6, lane = tid & 63;
  int quad = lane >> 4, l16 = lane & 15;
  int row0 = blockIdx.x * 128 + wave * 32;

  floatx4 acc[2][CT];
#pragma unroll
  for (int rt = 0; rt < 2; rt++)
#pragma unroll
    for (int ct = 0; ct < CT; ct++) acc[rt][ct] = (floatx4)(0.f);

  const unsigned short* arow[2];
#pragma unroll
  for (int rt = 0; rt < 2; rt++) {
    int r = min(row0 + rt * 16 + l16, nrows - 1);
    arow[rt] = Ab + (size_t)r * K + quad * 8;
  }
#pragma unroll 4
  for (int f = tid; f < 16 * 128; f += 256) {
    int kq = f >> 7;
    int n = f & 127;
    *(bf16x8*)&SW[f * 8] = *(const bf16x8*)&Wp[(size_t)(kq * N + c0 + n) * 8];
  }
  __syncthreads();
#pragma unroll
  for (int kb = 0; kb < 4; ++kb) {
    bf16x8 av[2];
#pragma unroll
    for (int rt = 0; rt < 2; rt++)
      av[rt] = *(const bf16x8*)(arow[rt] + kb * 32);
#pragma unroll
    for (int ct = 0; ct < CT; ct++) {
      bf16x8 bh = *(bf16x8*)&SW[((kb * 4 + quad) * 128 + ct * 16 + l16) * 8];
#pragma unroll
      for (int rt = 0; rt < 2; rt++)
        acc[rt][ct] = __builtin_amdgcn_mfma_f32_16x16x32_bf16(av[rt], bh, acc[rt][ct], 0, 0, 0);
    }
  }
#pragma unroll
  for (int ct = 0; ct < CT; ct++) {
    float bvv = bias[ct * 16 + l16];
    int col = c0 + ct * 16 + l16;
#pragma unroll
    for (int rt = 0; rt < 2; rt++)
#pragma unroll
      for (int i = 0; i < 4; i++) {
        int r = row0 + rt * 16 + quad * 4 + i;
        if (r < nrows)
          out[(size_t)r * 384 + col] = f2bf(acc[rt][ct][i] + bvv);
      }
  }
}

// ---------------- FFN1 GEMM: bf16 A, hi/lo W (2 MFMA), relu, bf16 out (N=256) ----------------
__global__ __launch_bounds__(256) void mfma_gemm_ffn1(
    const unsigned short* __restrict__ Ab,
    const unsigned short* __restrict__ Wp,
    const float* __restrict__ bias,
    unsigned short* __restrict__ out, int nrows)
{
  constexpr int K = 128, N = 256, CT = 8;
  __shared__ unsigned short SW[2 * 16 * 128 * 8];  // 64 KB
  int tid = threadIdx.x;
  int c0 = blockIdx.y * 128;
  int wave = tid >> 6, lane = tid & 63;
  int quad = lane >> 4, l16 = lane & 15;
  int row0 = blockIdx.x * 128 + wave * 32;

  floatx4 acc[2][CT];
#pragma unroll
  for (int rt = 0; rt < 2; rt++)
#pragma unroll
    for (int ct = 0; ct < CT; ct++) acc[rt][ct] = (floatx4)(0.f);

  const unsigned short* arow[2];
#pragma unroll
  for (int rt = 0; rt < 2; rt++) {
    int r = min(row0 + rt * 16 + l16, nrows - 1);
    arow[rt] = Ab + (size_t)r * K + quad * 8;
  }
  const int planeStride = K * N;
#pragma unroll 4
  for (int f = tid; f < 2 * 16 * 128; f += 256) {
    int p = f >> 11;
    int rem = f & 2047;
    int kq = rem >> 7;
    int n = rem & 127;
    *(bf16x8*)&SW[f * 8] =
        *(const bf16x8*)&Wp[(size_t)p * planeStride + (size_t)(kq * N + c0 + n) * 8];
  }
  __syncthreads();
#pragma unroll
  for (int kb = 0; kb < 4; ++kb) {
    bf16x8 av[2];
#pragma unroll
    for (int rt = 0; rt < 2; rt++)
      av[rt] = *(const bf16x8*)(arow[rt] + kb * 32);
#pragma unroll
    for (int ct = 0; ct < CT; ct++) {
      int base = ((kb * 4 + quad) * 128 + ct * 16 + l16) * 8;
      bf16x8 bh = *(bf16x8*)&SW[base];
      bf16x8 bl = *(bf16x8*)&SW[16 * 128 * 8 + base];
#pragma unroll
      for (int rt = 0; rt < 2; rt++) {
        acc[rt][ct] = __builtin_amdgcn_mfma_f32_16x16x32_bf16(av[rt], bh, acc[rt][ct], 0, 0, 0);
        acc[rt][ct] = __builtin_amdgcn_mfma_f32_16x16x32_bf16(av[rt], bl, acc[rt][ct], 0, 0, 0);
      }
    }
  }
#pragma unroll
  for (int ct = 0; ct < CT; ct++) {
    int col = c0 + ct * 16 + l16;
    float bvv = bias[col];
#pragma unroll
    for (int rt = 0; rt < 2; rt++)
#pragma unroll
      for (int i = 0; i < 4; i++) {
        int r = row0 + rt * 16 + quad * 4 + i;
        if (r < nrows)
          out[(size_t)r * 256 + col] = f2bf(fmaxf(acc[rt][ct][i] + bvv, 0.f));
      }
  }
}

// ---------------- GEMM + fused residual LN (bf16 residual): hi/lo W (2 MFMA) ----------------
// y = A@W + bias; if STORE_Y: yout(bf16) = y;  xres = bf16(LN(xres + y)*g + b)
template<int K, bool STORE_Y>
__global__ __launch_bounds__(256) void mfma_gemm_ln(
    const unsigned short* __restrict__ Ab,
    const unsigned short* __restrict__ Wp,
    const float* __restrict__ bias,
    unsigned short* __restrict__ xres,
    unsigned short* __restrict__ yout,
    const float* __restrict__ g, const float* __restrict__ b, int nrows)
{
  constexpr int N = 128, CT = 8;
  __shared__ unsigned short SW[2 * 16 * 128 * 8];  // 64 KB chunk
  int tid = threadIdx.x;
  int wave = tid >> 6, lane = tid & 63;
  int quad = lane >> 4, l16 = lane & 15;
  int row0 = blockIdx.x * 128 + wave * 32;

  floatx4 acc[2][CT];
#pragma unroll
  for (int rt = 0; rt < 2; rt++)
#pragma unroll
    for (int ct = 0; ct < CT; ct++) acc[rt][ct] = (floatx4)(0.f);

  const unsigned short* arow[2];
#pragma unroll
  for (int rt = 0; rt < 2; rt++) {
    int r = min(row0 + rt * 16 + l16, nrows - 1);
    arow[rt] = Ab + (size_t)r * K + quad * 8;
  }
  const int planeStride = K * N;

  for (int kc0 = 0; kc0 < K; kc0 += 128) {
    __syncthreads();
#pragma unroll 4
    for (int f = tid; f < 2 * 16 * 128; f += 256) {
      int p = f >> 11;
      int rem = f & 2047;
      int kq = rem >> 7;
      int n = rem & 127;
      *(bf16x8*)&SW[f * 8] =
          *(const bf16x8*)&Wp[(size_t)p * planeStride +
                              (size_t)((kc0 / 8 + kq) * N + n) * 8];
    }
    __syncthreads();
#pragma unroll
    for (int kb = 0; kb < 4; ++kb) {
      bf16x8 av[2];
#pragma unroll
      for (int rt = 0; rt < 2; rt++)
        av[rt] = *(const bf16x8*)(arow[rt] + kc0 + kb * 32);
#pragma unroll
      for (int ct = 0; ct < CT; ct++) {
        int base = ((kb * 4 + quad) * 128 + ct * 16 + l16) * 8;
        bf16x8 bh = *(bf16x8*)&SW[base];
        bf16x8 bl = *(bf16x8*)&SW[16 * 128 * 8 + base];
#pragma unroll
        for (int rt = 0; rt < 2; rt++) {
          acc[rt][ct] = __builtin_amdgcn_mfma_f32_16x16x32_bf16(av[rt], bh, acc[rt][ct], 0, 0, 0);
          acc[rt][ct] = __builtin_amdgcn_mfma_f32_16x16x32_bf16(av[rt], bl, acc[rt][ct], 0, 0, 0);
        }
      }
    }
  }

  float gv[CT], bvv[CT], biasv[CT];
#pragma unroll
  for (int ct = 0; ct < CT; ct++) {
    int col = ct * 16 + l16;
    gv[ct] = g[col];
    bvv[ct] = b[col];
    biasv[ct] = bias[col];
  }
#pragma unroll
  for (int rt = 0; rt < 2; rt++) {
#pragma unroll
    for (int i = 0; i < 4; i++) {
      int r = row0 + rt * 16 + quad * 4 + i;
      int rl = min(r, nrows - 1);
      float t[CT];
      float s = 0.f;
#pragma unroll
      for (int ct = 0; ct < CT; ct++) {
        float yv = acc[rt][ct][i] + biasv[ct];
        if (STORE_Y && r < nrows) yout[(size_t)r * 128 + ct * 16 + l16] = f2bf(yv);
        t[ct] = yv + bf2f(xres[(size_t)rl * 128 + ct * 16 + l16]);
        s += t[ct];
      }
      s += __shfl_xor(s, 1); s += __shfl_xor(s, 2);
      s += __shfl_xor(s, 4); s += __shfl_xor(s, 8);
      float mean = s * (1.f / 128.f);
      float vv = 0.f;
#pragma unroll
      for (int ct = 0; ct < CT; ct++) {
        float d = t[ct] - mean;
        vv += d * d;
      }
      vv += __shfl_xor(vv, 1); vv += __shfl_xor(vv, 2);
      vv += __shfl_xor(vv, 4); vv += __shfl_xor(vv, 8);
      float inv = rsqrtf(vv * (1.f / 128.f) + 1e-5f);
      if (r < nrows) {
#pragma unroll
        for (int ct = 0; ct < CT; ct++) {
          float o = (t[ct] - mean) * inv * gv[ct] + bvv[ct];
          xres[(size_t)r * 128 + ct * 16 + l16] = f2bf(o);
        }
      }
    }
  }
}

// ---------------- fused edge attention (bf16 qkv), one wave per dst node, x4 unroll ----------------
__global__ __launch_bounds__(256) void attn_kernel(
    const unsigned short* __restrict__ qkv,
    const int* __restrict__ offsets, const int* __restrict__ csr,
    unsigned short* __restrict__ attn)
{
  int node = blockIdx.x * 4 + (threadIdx.x >> 6);
  int lane = threadIdx.x & 63;
  if (node >= N_NODES) return;
  float2 q2 = bf2f2(*(const unsigned int*)(qkv + (size_t)node * 384 + lane * 2));
  float wx = 0.f, wy = 0.f, z = 0.f;
  int j = offsets[node], end = offsets[node + 1];
  for (; j + 4 <= end; j += 4) {
    int4 s4 = *(const int4*)(csr + j);   // csr offsets not 16B-aligned per node; use scalar loads
    const unsigned short* r0 = qkv + (size_t)s4.x * 384 + 128;
    const unsigned short* r1 = qkv + (size_t)s4.y * 384 + 128;
    const unsigned short* r2 = qkv + (size_t)s4.z * 384 + 128;
    const unsigned short* r3 = qkv + (size_t)s4.w * 384 + 128;
    unsigned int ku0 = *(const unsigned int*)(r0 + lane * 2);
    unsigned int ku1 = *(const unsigned int*)(r1 + lane * 2);
    unsigned int ku2 = *(const unsigned int*)(r2 + lane * 2);
    unsigned int ku3 = *(const unsigned int*)(r3 + lane * 2);
    unsigned int vu0 = *(const unsigned int*)(r0 + 128 + lane * 2);
    unsigned int vu1 = *(const unsigned int*)(r1 + 128 + lane * 2);
    unsigned int vu2 = *(const unsigned int*)(r2 + 128 + lane * 2);
    unsigned int vu3 = *(const unsigned int*)(r3 + 128 + lane * 2);
    float2 k0 = bf2f2(ku0), k1 = bf2f2(ku1), k2 = bf2f2(ku2), k3 = bf2f2(ku3);
    float p0 = k0.x * q2.x + k0.y * q2.y;
    float p1 = k1.x * q2.x + k1.y * q2.y;
    float p2 = k2.x * q2.x + k2.y * q2.y;
    float p3 = k3.x * q2.x + k3.y * q2.y;
    p0 += __shfl_xor(p0, 1); p1 += __shfl_xor(p1, 1);
    p2 += __shfl_xor(p2, 1); p3 += __shfl_xor(p3, 1);
    p0 += __shfl_xor(p0, 2); p1 += __shfl_xor(p1, 2);
    p2 += __shfl_xor(p2, 2); p3 += __shfl_xor(p3, 2);
    p0 += __shfl_xor(p0, 4); p1 += __shfl_xor(p1, 4);
    p2 += __shfl_xor(p2, 4); p3 += __shfl_xor(p3, 4);
    float sc0 = __expf(fminf(fmaxf(p0 * 0.25f, -5.f), 5.f));
    float sc1 = __expf(fminf(fmaxf(p1 * 0.25f, -5.f), 5.f));
    float sc2 = __expf(fminf(fmaxf(p2 * 0.25f, -5.f), 5.f));
    float sc3 = __expf(fminf(fmaxf(p3 * 0.25f, -5.f), 5.f));
    float2 v0 = bf2f2(vu0), v1 = bf2f2(vu1), v2 = bf2f2(vu2), v3 = bf2f2(vu3);
    wx = fmaf(sc0, v0.x, wx); wy = fmaf(sc0, v0.y, wy);
    wx = fmaf(sc1, v1.x, wx); wy = fmaf(sc1, v1.y, wy);
    wx = fmaf(sc2, v2.x, wx); wy = fmaf(sc2, v2.y, wy);
    wx = fmaf(sc3, v3.x, wx); wy = fmaf(sc3, v3.y, wy);
    z += (sc0 + sc1) + (sc2 + sc3);
  }
  for (; j < end; ++j) {
    int s = csr[j];
    const unsigned short* r0 = qkv + (size_t)s * 384 + 128;
    float2 k2 = bf2f2(*(const unsigned int*)(r0 + lane * 2));
    float p = k2.x * q2.x + k2.y * q2.y;
    p += __shfl_xor(p, 1); p += __shfl_xor(p, 2); p += __shfl_xor(p, 4);
    float sc = __expf(fminf(fmaxf(p * 0.25f, -5.f), 5.f));
    float2 v2 = bf2f2(*(const unsigned int*)(r0 + 128 + lane * 2));
    wx = fmaf(sc, v2.x, wx); wy = fmaf(sc, v2.y, wy);
    z += sc;
  }
  float inv = 1.f / (z + 1e-6f);
  unsigned int pack = (unsigned int)f2bf(wx * inv) | ((unsigned int)f2bf(wy * inv) << 16);
  *(unsigned int*)(attn + (size_t)node * DIM + lane * 2) = pack;
}

// ---------------- column mean over nodes (bf16 in, fp32 acc) ----------------
__global__ __launch_bounds__(256) void colmean_kernel(
    const unsigned short* __restrict__ xb, float* __restrict__ mean)
{
  int col = threadIdx.x & 127;
  int half = threadIdx.x >> 7;
  float acc = 0.f;
  for (int r = blockIdx.x * 2 + half; r < N_NODES; r += gridDim.x * 2)
    acc += bf2f(xb[(size_t)r * DIM + col]);
  __shared__ float s[256];
  s[threadIdx.x] = acc;
  __syncthreads();
  if (threadIdx.x < 128) atomicAdd(&mean[col], s[threadIdx.x] + s[threadIdx.x + 128]);
}

// ---------------- readout MLP 128->64->32->10 ----------------
__global__ void readout_kernel(
    const float* __restrict__ mean,
    const float* __restrict__ mW0, const float* __restrict__ mb0,
    const float* __restrict__ mW1, const float* __restrict__ mb1,
    const float* __restrict__ mW2, const float* __restrict__ mb2,
    float* __restrict__ out)
{
  __shared__ float sx[128], h0[64], h1[32];
  int t = threadIdx.x;
  sx[t] = mean[t] * (1.f / (float)N_NODES);
  __syncthreads();
  if (t < 64) {
    float a = mb0[t];
    for (int i = 0; i < 128; i++) a = fmaf(sx[i], mW0[i * 64 + t], a);
    h0[t] = fmaxf(a, 0.f);
  }
  __syncthreads();
  if (t < 32) {
    float a = mb1[t];
    for (int i = 0; i < 64; i++) a = fmaf(h0[i], mW1[i * 32 + t], a);
    h1[t] = fmaxf(a, 0.f);
  }
  __syncthreads();
  if (t < 10) {
    float a = mb2[t];
    for (int i = 0; i < 32; i++) a = fmaf(h1[i], mW2[i * 10 + t], a);
    out[t] = a;
  }
}

extern "C" void kernel_launch(void* const* d_in, const int* in_sizes, int n_in,
                              void* d_out, int out_size, void* d_ws, size_t ws_size,
                              hipStream_t stream) {
  const int*   x_idx = (const int*)d_in[0];
  const int*   eidx  = (const int*)d_in[1];
  const float* emb   = (const float*)d_in[2];
  const float* Wq = (const float*)d_in[3];  const float* bq = (const float*)d_in[4];
  const float* Wk = (const float*)d_in[5];  const float* bk = (const float*)d_in[6];
  const float* Wv = (const float*)d_in[7];  const float* bv = (const float*)d_in[8];
  const float* Wo = (const float*)d_in[9];  const float* bo = (const float*)d_in[10];
  const float* g1 = (const float*)d_in[11]; const float* be1 = (const float*)d_in[12];
  const float* Wf1 = (const float*)d_in[13]; const float* bf1 = (const float*)d_in[14];
  const float* Wf2 = (const float*)d_in[15]; const float* bf2 = (const float*)d_in[16];
  const float* g2 = (const float*)d_in[17]; const float* be2 = (const float*)d_in[18];
  const float* mW0 = (const float*)d_in[19]; const float* mb0 = (const float*)d_in[20];
  const float* mW1 = (const float*)d_in[21]; const float* mb1 = (const float*)d_in[22];
  const float* mW2 = (const float*)d_in[23]; const float* mb2 = (const float*)d_in[24];
  float* out = (float*)d_out;

  const size_t NX = (size_t)N_NODES * DIM;
  unsigned short* xb  = (unsigned short*)d_ws;                // bf16 residual
  unsigned short* qkv = xb + NX;                              // [N,384] bf16
  unsigned short* a   = qkv + (size_t)N_NODES * 384;          // attn out bf16
  unsigned short* y   = a + NX;                               // attn proj bf16
  unsigned short* ffh = y + NX;                               // [N,256] bf16

  unsigned short* wqkv_p = ffh + (size_t)N_NODES * 256;       // 3*128*384 (single)
  unsigned short* wo_p   = wqkv_p + 3 * 128 * 384;            // 3*2*128*128
  unsigned short* wf1_p  = wo_p   + 3 * 2 * 128 * 128;        // 3*2*128*256
  unsigned short* wf2_p  = wf1_p  + 3 * 2 * 128 * 256;        // 3*2*256*128
  unsigned short* wend   = wf2_p  + 3 * 2 * 256 * 128;

  // zeroed region: counts | fill | meanb  (single memset)
  int* counts  = (int*)wend;
  int* fill    = counts + N_NODES;
  float* meanb = (float*)(fill + N_NODES);
  int* offsets = (int*)(meanb + DIM);
  int* bsums   = offsets + N_NODES + 1;
  int* csr     = bsums + 256;

  const int* e0 = eidx;
  const int* e1 = eidx + N_EDGES;

  hipMemsetAsync(counts, 0, (2 * N_NODES + DIM) * sizeof(int), stream);

  prep_weights1<<<24, 256, 0, stream>>>(Wq, wqkv_p, 128, 128, 384, 0, 3);
  prep_weights1<<<24, 256, 0, stream>>>(Wk, wqkv_p, 128, 128, 384, 128, 3);
  prep_weights1<<<24, 256, 0, stream>>>(Wv, wqkv_p, 128, 128, 384, 256, 3);
  prep_weights2<<<24, 256, 0, stream>>>(Wo, wo_p, 128, 128, 128, 0, 3);
  prep_weights2<<<48, 256, 0, stream>>>(Wf1, wf1_p, 128, 256, 256, 0, 3);
  prep_weights2<<<48, 256, 0, stream>>>(Wf2, wf2_p, 256, 128, 128, 0, 3);

  embed_kernel<<<(N_NODES * 32 + 255) / 256, 256, 0, stream>>>(x_idx, emb, xb);
  hist_kernel<<<(N_EDGES + 255) / 256, 256, 0, stream>>>(e1, counts);
  int nblk = (N_NODES + 255) / 256;
  scan_local<<<nblk, 256, 0, stream>>>(counts, offsets, bsums);
  scan_bsums<<<1, 256, 0, stream>>>(bsums, nblk);
  scan_add<<<nblk, 256, 0, stream>>>(offsets, bsums);
  scatter_kernel<<<(N_EDGES + 255) / 256, 256, 0, stream>>>(e0, e1, offsets, fill, csr);

  int gx = (N_NODES + 127) / 128;   // 391
  int nb4 = (N_NODES + 3) / 4;

  for (int l = 0; l < NLAYERS; ++l) {
    const unsigned short* wqkv_l = wqkv_p + (size_t)l * 128 * 384;
    const unsigned short* wo_l   = wo_p   + (size_t)l * 2 * 128 * 128;
    const unsigned short* wf1_l  = wf1_p  + (size_t)l * 2 * 128 * 256;
    const unsigned short* wf2_l  = wf2_p  + (size_t)l * 2 * 256 * 128;
    const float* bq_l = bq + (size_t)l * DIM;
    const float* bk_l = bk + (size_t)l * DIM;
    const float* bv_l = bv + (size_t)l * DIM;
    const float* bo_l = bo + (size_t)l * DIM;
    const float* bf1_l = bf1 + (size_t)l * 2 * DIM;
    const float* bf2_l = bf2 + (size_t)l * DIM;

    mfma_gemm_qkv<<<dim3(gx, 3), 256, 0, stream>>>(xb, wqkv_l, bq_l, bk_l, bv_l, qkv, N_NODES);
    attn_kernel<<<nb4, 256, 0, stream>>>(qkv, offsets, csr, a);
    mfma_gemm_ln<128, true><<<dim3(gx, 1), 256, 0, stream>>>(
        a, wo_l, bo_l, xb, y, g1 + (size_t)l * DIM, be1 + (size_t)l * DIM, N_NODES);
    mfma_gemm_ffn1<<<dim3(gx, 2), 256, 0, stream>>>(y, wf1_l, bf1_l, ffh, N_NODES);
    mfma_gemm_ln<256, false><<<dim3(gx, 1), 256, 0, stream>>>(
        ffh, wf2_l, bf2_l, xb, nullptr, g2 + (size_t)l * DIM, be2 + (size_t)l * DIM, N_NODES);
  }

  colmean_kernel<<<128, 256, 0, stream>>>(xb, meanb);
  readout_kernel<<<1, 128, 0, stream>>>(meanb, mW0, mb0, mW1, mb1, mW2, mb2, out);
}

// Round 6
// 719.393 us; speedup vs baseline: 2.7360x; 1.0321x over previous
//
#include <hip/hip_runtime.h>
#include <hip/hip_bf16.h>

#define N_NODES 50000
#define N_EDGES 800000
#define DIM 128
#define NLAYERS 3

typedef short bf16x8 __attribute__((ext_vector_type(8)));
typedef float floatx4 __attribute__((ext_vector_type(4)));

__device__ __forceinline__ unsigned short f2bf(float f) {
  unsigned int u = __builtin_bit_cast(unsigned int, f);
  return (unsigned short)((u + 0x7FFFu + ((u >> 16) & 1u)) >> 16);
}
__device__ __forceinline__ float bf2f(unsigned short h) {
  return __builtin_bit_cast(float, (unsigned int)h << 16);
}
__device__ __forceinline__ float bfhi(float f, unsigned short& hb) {
  unsigned int u = __builtin_bit_cast(unsigned int, f);
  unsigned int r = (u + 0x7FFFu + ((u >> 16) & 1u)) & 0xFFFF0000u;
  hb = (unsigned short)(r >> 16);
  return __builtin_bit_cast(float, r);
}
__device__ __forceinline__ float2 bf2f2(unsigned int u) {
  float lo = __builtin_bit_cast(float, u << 16);
  float hi = __builtin_bit_cast(float, u & 0xFFFF0000u);
  return make_float2(lo, hi);
}

// ---------------- embedding gather -> bf16 residual ----------------
__global__ __launch_bounds__(256) void embed_kernel(
    const int* __restrict__ idx, const float* __restrict__ emb,
    unsigned short* __restrict__ xb)
{
  int gid = blockIdx.x * 256 + threadIdx.x;
  int n = gid >> 5;
  int c = (gid & 31) << 2;
  if (n >= N_NODES) return;
  int e = idx[n];
  float4 val = *(const float4*)(emb + (size_t)e * DIM + c);
  ushort4 pk;
  pk.x = f2bf(val.x); pk.y = f2bf(val.y); pk.z = f2bf(val.z); pk.w = f2bf(val.w);
  *(ushort4*)(xb + (size_t)n * DIM + c) = pk;
}

// ---------------- CSR build ----------------
__global__ __launch_bounds__(256) void hist_kernel(
    const int* __restrict__ e1, int* __restrict__ counts)
{
  int i = blockIdx.x * 256 + threadIdx.x;
  if (i < N_EDGES) atomicAdd(&counts[e1[i]], 1);
}

__global__ __launch_bounds__(256) void scan_local(
    const int* __restrict__ counts, int* __restrict__ offsets,
    int* __restrict__ bsums)
{
  __shared__ int buf[256];
  int t = threadIdx.x;
  int i = blockIdx.x * 256 + t;
  int v = (i < N_NODES) ? counts[i] : 0;
  buf[t] = v;
  __syncthreads();
  int s = v;
#pragma unroll
  for (int off = 1; off < 256; off <<= 1) {
    int t2 = (t >= off) ? buf[t - off] : 0;
    __syncthreads();
    s += t2;
    buf[t] = s;
    __syncthreads();
  }
  if (i < N_NODES) offsets[i] = s - v;
  if (t == 255) bsums[blockIdx.x] = s;
}

__global__ void scan_bsums(int* __restrict__ bsums, int nblk)
{
  __shared__ int buf[256];
  int t = threadIdx.x;
  int v = (t < nblk) ? bsums[t] : 0;
  buf[t] = v;
  __syncthreads();
  int s = v;
#pragma unroll
  for (int off = 1; off < 256; off <<= 1) {
    int t2 = (t >= off) ? buf[t - off] : 0;
    __syncthreads();
    s += t2;
    buf[t] = s;
    __syncthreads();
  }
  if (t < nblk) bsums[t] = s - v;
}

__global__ __launch_bounds__(256) void scan_add(
    int* __restrict__ offsets, const int* __restrict__ bsums)
{
  int i = blockIdx.x * 256 + threadIdx.x;
  if (i < N_NODES) offsets[i] += bsums[blockIdx.x];
  if (i == 0) offsets[N_NODES] = N_EDGES;
}

__global__ __launch_bounds__(256) void scatter_kernel(
    const int* __restrict__ e0, const int* __restrict__ e1,
    const int* __restrict__ offsets, int* __restrict__ fill,
    int* __restrict__ csr)
{
  int i = blockIdx.x * 256 + threadIdx.x;
  if (i >= N_EDGES) return;
  int d = e1[i];
  int pos = offsets[d] + atomicAdd(&fill[d], 1);
  csr[pos] = e0[i];
}

// ---------------- weight prep ----------------
__global__ __launch_bounds__(256) void prep_weights2(
    const float* __restrict__ W, unsigned short* __restrict__ out,
    int K, int Nsrc, int Ndst, int c0, int L)
{
  int g = blockIdx.x * 256 + threadIdx.x;
  int fragsPerMat = (K / 8) * Nsrc;
  int total = L * fragsPerMat;
  if (g >= total) return;
  int l = g / fragsPerMat;
  int rem = g - l * fragsPerMat;
  int kq = rem / Nsrc;
  int n = rem - kq * Nsrc;
  const float* Wl = W + (size_t)l * K * Nsrc;
  unsigned short* basehi = out + (size_t)l * 2 * K * Ndst + (size_t)(kq * Ndst + c0 + n) * 8;
  unsigned short* baselo = basehi + (size_t)K * Ndst;
#pragma unroll
  for (int j = 0; j < 8; j++) {
    float f = Wl[(size_t)(kq * 8 + j) * Nsrc + n];
    unsigned short hb;
    float hf = bfhi(f, hb);
    basehi[j] = hb;
    baselo[j] = f2bf(f - hf);
  }
}

__global__ __launch_bounds__(256) void prep_weights1(
    const float* __restrict__ W, unsigned short* __restrict__ out,
    int K, int Nsrc, int Ndst, int c0, int L)
{
  int g = blockIdx.x * 256 + threadIdx.x;
  int fragsPerMat = (K / 8) * Nsrc;
  int total = L * fragsPerMat;
  if (g >= total) return;
  int l = g / fragsPerMat;
  int rem = g - l * fragsPerMat;
  int kq = rem / Nsrc;
  int n = rem - kq * Nsrc;
  const float* Wl = W + (size_t)l * K * Nsrc;
  unsigned short* base = out + (size_t)l * K * Ndst + (size_t)(kq * Ndst + c0 + n) * 8;
#pragma unroll
  for (int j = 0; j < 8; j++)
    base[j] = f2bf(Wl[(size_t)(kq * 8 + j) * Nsrc + n]);
}

// ---------------- QKV GEMM (layer 0 only): bf16 A, single-plane W, bf16 out ----------------
__global__ __launch_bounds__(256) void mfma_gemm_qkv(
    const unsigned short* __restrict__ Ab,
    const unsigned short* __restrict__ Wp,
    const float* __restrict__ bq, const float* __restrict__ bk,
    const float* __restrict__ bv,
    unsigned short* __restrict__ out, int nrows)
{
  constexpr int K = 128, N = 384, CT = 8;
  __shared__ unsigned short SW[16 * 128 * 8];   // 32 KB
  int tid = threadIdx.x;
  int c0 = blockIdx.y * 128;
  const float* bias = (blockIdx.y == 0) ? bq : (blockIdx.y == 1) ? bk : bv;
  int wave = tid >> 6, lane = tid & 63;
  int quad = lane >> 4, l16 = lane & 15;
  int row0 = blockIdx.x * 128 + wave * 32;

  floatx4 acc[2][CT];
#pragma unroll
  for (int rt = 0; rt < 2; rt++)
#pragma unroll
    for (int ct = 0; ct < CT; ct++) acc[rt][ct] = (floatx4)(0.f);

  const unsigned short* arow[2];
#pragma unroll
  for (int rt = 0; rt < 2; rt++) {
    int r = min(row0 + rt * 16 + l16, nrows - 1);
    arow[rt] = Ab + (size_t)r * K + quad * 8;
  }
#pragma unroll 4
  for (int f = tid; f < 16 * 128; f += 256) {
    int kq = f >> 7;
    int n = f & 127;
    *(bf16x8*)&SW[f * 8] = *(const bf16x8*)&Wp[(size_t)(kq * N + c0 + n) * 8];
  }
  __syncthreads();
#pragma unroll
  for (int kb = 0; kb < 4; ++kb) {
    bf16x8 av[2];
#pragma unroll
    for (int rt = 0; rt < 2; rt++)
      av[rt] = *(const bf16x8*)(arow[rt] + kb * 32);
#pragma unroll
    for (int ct = 0; ct < CT; ct++) {
      bf16x8 bh = *(bf16x8*)&SW[((kb * 4 + quad) * 128 + ct * 16 + l16) * 8];
#pragma unroll
      for (int rt = 0; rt < 2; rt++)
        acc[rt][ct] = __builtin_amdgcn_mfma_f32_16x16x32_bf16(av[rt], bh, acc[rt][ct], 0, 0, 0);
    }
  }
#pragma unroll
  for (int ct = 0; ct < CT; ct++) {
    float bvv = bias[ct * 16 + l16];
    int col = c0 + ct * 16 + l16;
#pragma unroll
    for (int rt = 0; rt < 2; rt++)
#pragma unroll
      for (int i = 0; i < 4; i++) {
        int r = row0 + rt * 16 + quad * 4 + i;
        if (r < nrows)
          out[(size_t)r * 384 + col] = f2bf(acc[rt][ct][i] + bvv);
      }
  }
}

// ================ fused dense chain: O-GEMM + LN1 + FFN1 + FFN2 + LN2 (+QKV next) ================
// 64 rows/block, 4 waves (each wave owns 16 rows). LDS: WBUF 32K + Y 16K + F 16K = 64 KB.
// Weights are hi/lo frag-major (O, FFN1, FFN2) and single-plane (QKV next).
// x1 (post-LN1 residual) lives in registers. C-layout: col=ctmap, row=quad*4+i.
template<bool LAST>
__global__ __launch_bounds__(256) void chain_kernel(
    const unsigned short* __restrict__ a,     // [N,128] attn out
    unsigned short* __restrict__ xb,          // [N,128] residual in (h) / out (x2)
    unsigned short* __restrict__ qkv,         // [N,384] out: next-layer qkv
    const unsigned short* __restrict__ wo, const float* __restrict__ bo,
    const float* __restrict__ g1, const float* __restrict__ be1,
    const unsigned short* __restrict__ wf1, const float* __restrict__ bf1,
    const unsigned short* __restrict__ wf2, const float* __restrict__ bf2,
    const float* __restrict__ g2, const float* __restrict__ be2,
    const unsigned short* __restrict__ wqkv,
    const float* __restrict__ bq, const float* __restrict__ bk,
    const float* __restrict__ bv, int nrows)
{
  __shared__ unsigned short WBUF[16384];  // 32 KB weight staging
  __shared__ unsigned short Y[64 * 128];  // 16 KB (y, later x2)
  __shared__ unsigned short F[64 * 128];  // 16 KB (ffh col-half)
  int tid = threadIdx.x;
  int wave = tid >> 6, lane = tid & 63;
  int quad = lane >> 4, l16 = lane & 15;
  int rbase = blockIdx.x * 64;
  int wrow = wave * 16;

  // A-frags for O-GEMM from global a
  int grA = min(rbase + wrow + l16, nrows - 1);
  bf16x8 avO[4];
#pragma unroll
  for (int kb = 0; kb < 4; kb++)
    avO[kb] = *(const bf16x8*)(a + (size_t)grA * 128 + kb * 32 + quad * 8);

  // column map for acc index cc in [0,8): col = (cc>>2)*64 + (cc&3)*16 + l16
#define COLOF(cc) (((cc) >> 2) * 64 + ((cc) & 3) * 16 + l16)

  // ---- O-GEMM (K=128, N=128, hi/lo): two 64-col halves ----
  floatx4 accO[8];
#pragma unroll
  for (int cc = 0; cc < 8; cc++) accO[cc] = (floatx4)(0.f);
#pragma unroll
  for (int ch = 0; ch < 2; ch++) {
    __syncthreads();
    for (int f = tid; f < 2048; f += 256) {
      int p = f >> 10, rem = f & 1023, kq = rem >> 6, n = rem & 63;
      *(bf16x8*)&WBUF[f * 8] =
          *(const bf16x8*)&wo[(size_t)p * (128 * 128) + (size_t)(kq * 128 + ch * 64 + n) * 8];
    }
    __syncthreads();
#pragma unroll
    for (int kb = 0; kb < 4; kb++) {
#pragma unroll
      for (int ct = 0; ct < 4; ct++) {
        int base = ((kb * 4 + quad) * 64 + ct * 16 + l16) * 8;
        bf16x8 bh = *(bf16x8*)&WBUF[base];
        bf16x8 bl = *(bf16x8*)&WBUF[8192 + base];
        accO[ch * 4 + ct] = __builtin_amdgcn_mfma_f32_16x16x32_bf16(avO[kb], bh, accO[ch * 4 + ct], 0, 0, 0);
        accO[ch * 4 + ct] = __builtin_amdgcn_mfma_f32_16x16x32_bf16(avO[kb], bl, accO[ch * 4 + ct], 0, 0, 0);
      }
    }
  }

  // ---- LN1: x1 = LN(h + y) (x1 in regs); y -> Y LDS ----
  float x1v[8][4];
  {
    float biasO[8], g1v[8], b1v[8];
#pragma unroll
    for (int cc = 0; cc < 8; cc++) {
      int col = COLOF(cc);
      biasO[cc] = bo[col]; g1v[cc] = g1[col]; b1v[cc] = be1[col];
    }
#pragma unroll
    for (int i = 0; i < 4; i++) {
      int lrow = wrow + quad * 4 + i;
      int grow = min(rbase + lrow, nrows - 1);
      float t[8]; float s = 0.f;
#pragma unroll
      for (int cc = 0; cc < 8; cc++) {
        float yv = accO[cc][i] + biasO[cc];
        Y[lrow * 128 + COLOF(cc)] = f2bf(yv);
        t[cc] = yv + bf2f(xb[(size_t)grow * 128 + COLOF(cc)]);
        s += t[cc];
      }
      s += __shfl_xor(s, 1); s += __shfl_xor(s, 2);
      s += __shfl_xor(s, 4); s += __shfl_xor(s, 8);
      float mean = s * (1.f / 128.f);
      float vv = 0.f;
#pragma unroll
      for (int cc = 0; cc < 8; cc++) { float d = t[cc] - mean; vv += d * d; }
      vv += __shfl_xor(vv, 1); vv += __shfl_xor(vv, 2);
      vv += __shfl_xor(vv, 4); vv += __shfl_xor(vv, 8);
      float inv = rsqrtf(vv * (1.f / 128.f) + 1e-5f);
#pragma unroll
      for (int cc = 0; cc < 8; cc++)
        x1v[cc][i] = (t[cc] - mean) * inv * g1v[cc] + b1v[cc];
    }
  }
  __syncthreads();   // Y ready
  bf16x8 avY[4];
#pragma unroll
  for (int kb = 0; kb < 4; kb++)
    avY[kb] = *(bf16x8*)&Y[(wrow + l16) * 128 + kb * 32 + quad * 8];

  // ---- FFN1 (K=128,N=256) interleaved with FFN2 (K=256,N=128) partial accumulation ----
  floatx4 acc2[8];
#pragma unroll
  for (int cc = 0; cc < 8; cc++) acc2[cc] = (floatx4)(0.f);
#pragma unroll
  for (int h = 0; h < 2; h++) {
    floatx4 accF[8];
#pragma unroll
    for (int cc = 0; cc < 8; cc++) accF[cc] = (floatx4)(0.f);
#pragma unroll
    for (int wch = 0; wch < 2; wch++) {
      __syncthreads();
      for (int f = tid; f < 2048; f += 256) {
        int p = f >> 10, rem = f & 1023, kq = rem >> 6, n = rem & 63;
        *(bf16x8*)&WBUF[f * 8] =
            *(const bf16x8*)&wf1[(size_t)p * (128 * 256) +
                                 (size_t)(kq * 256 + h * 128 + wch * 64 + n) * 8];
      }
      __syncthreads();
#pragma unroll
      for (int kb = 0; kb < 4; kb++) {
#pragma unroll
        for (int ct = 0; ct < 4; ct++) {
          int base = ((kb * 4 + quad) * 64 + ct * 16 + l16) * 8;
          bf16x8 bh = *(bf16x8*)&WBUF[base];
          bf16x8 bl = *(bf16x8*)&WBUF[8192 + base];
          accF[wch * 4 + ct] = __builtin_amdgcn_mfma_f32_16x16x32_bf16(avY[kb], bh, accF[wch * 4 + ct], 0, 0, 0);
          accF[wch * 4 + ct] = __builtin_amdgcn_mfma_f32_16x16x32_bf16(avY[kb], bl, accF[wch * 4 + ct], 0, 0, 0);
        }
      }
    }
    // relu + bias -> F (bf16)
    __syncthreads();  // prior F reads (FFN2 of previous h) done
#pragma unroll
    for (int i = 0; i < 4; i++) {
      int lrow = wrow + quad * 4 + i;
#pragma unroll
      for (int cc = 0; cc < 8; cc++) {
        float fv = fmaxf(accF[cc][i] + bf1[h * 128 + COLOF(cc)], 0.f);
        F[lrow * 128 + COLOF(cc)] = f2bf(fv);
      }
    }
    __syncthreads();  // F ready
    bf16x8 avF[4];
#pragma unroll
    for (int kb = 0; kb < 4; kb++)
      avF[kb] = *(bf16x8*)&F[(wrow + l16) * 128 + kb * 32 + quad * 8];
#pragma unroll
    for (int wch = 0; wch < 2; wch++) {
      __syncthreads();
      for (int f = tid; f < 2048; f += 256) {
        int p = f >> 10, rem = f & 1023, kq = rem >> 6, n = rem & 63;
        *(bf16x8*)&WBUF[f * 8] =
            *(const bf16x8*)&wf2[(size_t)p * (256 * 128) +
                                 (size_t)((h * 16 + kq) * 128 + wch * 64 + n) * 8];
      }
      __syncthreads();
#pragma unroll
      for (int kb = 0; kb < 4; kb++) {
#pragma unroll
        for (int ct = 0; ct < 4; ct++) {
          int base = ((kb * 4 + quad) * 64 + ct * 16 + l16) * 8;
          bf16x8 bh = *(bf16x8*)&WBUF[base];
          bf16x8 bl = *(bf16x8*)&WBUF[8192 + base];
          acc2[wch * 4 + ct] = __builtin_amdgcn_mfma_f32_16x16x32_bf16(avF[kb], bh, acc2[wch * 4 + ct], 0, 0, 0);
          acc2[wch * 4 + ct] = __builtin_amdgcn_mfma_f32_16x16x32_bf16(avF[kb], bl, acc2[wch * 4 + ct], 0, 0, 0);
        }
      }
    }
  }

  // ---- LN2: x2 = LN(x1 + ffn2) -> global xb; x2 -> Y (for QKV) ----
  {
    float bias2[8], g2v[8], b2v[8];
#pragma unroll
    for (int cc = 0; cc < 8; cc++) {
      int col = COLOF(cc);
      bias2[cc] = bf2[col]; g2v[cc] = g2[col]; b2v[cc] = be2[col];
    }
#pragma unroll
    for (int i = 0; i < 4; i++) {
      int lrow = wrow + quad * 4 + i;
      int grow = rbase + lrow;
      float t[8]; float s = 0.f;
#pragma unroll
      for (int cc = 0; cc < 8; cc++) {
        t[cc] = acc2[cc][i] + bias2[cc] + x1v[cc][i];
        s += t[cc];
      }
      s += __shfl_xor(s, 1); s += __shfl_xor(s, 2);
      s += __shfl_xor(s, 4); s += __shfl_xor(s, 8);
      float mean = s * (1.f / 128.f);
      float vv = 0.f;
#pragma unroll
      for (int cc = 0; cc < 8; cc++) { float d = t[cc] - mean; vv += d * d; }
      vv += __shfl_xor(vv, 1); vv += __shfl_xor(vv, 2);
      vv += __shfl_xor(vv, 4); vv += __shfl_xor(vv, 8);
      float inv = rsqrtf(vv * (1.f / 128.f) + 1e-5f);
#pragma unroll
      for (int cc = 0; cc < 8; cc++) {
        float o = (t[cc] - mean) * inv * g2v[cc] + b2v[cc];
        unsigned short ob = f2bf(o);
        Y[lrow * 128 + COLOF(cc)] = ob;
        if (grow < nrows) xb[(size_t)grow * 128 + COLOF(cc)] = ob;
      }
    }
  }
  if (!LAST) {
    __syncthreads();  // x2 in Y ready
    bf16x8 avQ[4];
#pragma unroll
    for (int kb = 0; kb < 4; kb++)
      avQ[kb] = *(bf16x8*)&Y[(wrow + l16) * 128 + kb * 32 + quad * 8];
#pragma unroll
    for (int c = 0; c < 3; c++) {
      __syncthreads();
      for (int f = tid; f < 2048; f += 256) {
        int kq = f >> 7, n = f & 127;
        *(bf16x8*)&WBUF[f * 8] =
            *(const bf16x8*)&wqkv[(size_t)(kq * 384 + c * 128 + n) * 8];
      }
      __syncthreads();
      floatx4 accQ[8];
#pragma unroll
      for (int ct = 0; ct < 8; ct++) accQ[ct] = (floatx4)(0.f);
#pragma unroll
      for (int kb = 0; kb < 4; kb++) {
#pragma unroll
        for (int ct = 0; ct < 8; ct++) {
          int base = ((kb * 4 + quad) * 128 + ct * 16 + l16) * 8;
          bf16x8 bh = *(bf16x8*)&WBUF[base];
          accQ[ct] = __builtin_amdgcn_mfma_f32_16x16x32_bf16(avQ[kb], bh, accQ[ct], 0, 0, 0);
        }
      }
      const float* bias = (c == 0) ? bq : (c == 1) ? bk : bv;
#pragma unroll
      for (int ct = 0; ct < 8; ct++) {
        float bvv = bias[ct * 16 + l16];
#pragma unroll
        for (int i = 0; i < 4; i++) {
          int grow = rbase + wrow + quad * 4 + i;
          if (grow < nrows)
            qkv[(size_t)grow * 384 + c * 128 + ct * 16 + l16] = f2bf(accQ[ct][i] + bvv);
        }
      }
    }
  }
#undef COLOF
}

// ---------------- fused edge attention (bf16 qkv), one wave per dst node, x4 unroll ----------------
__global__ __launch_bounds__(256) void attn_kernel(
    const unsigned short* __restrict__ qkv,
    const int* __restrict__ offsets, const int* __restrict__ csr,
    unsigned short* __restrict__ attn)
{
  int node = blockIdx.x * 4 + (threadIdx.x >> 6);
  int lane = threadIdx.x & 63;
  if (node >= N_NODES) return;
  float2 q2 = bf2f2(*(const unsigned int*)(qkv + (size_t)node * 384 + lane * 2));
  float wx = 0.f, wy = 0.f, z = 0.f;
  int j = offsets[node], end = offsets[node + 1];
  for (; j + 4 <= end; j += 4) {
    int4 s4 = *(const int4*)(csr + j);
    const unsigned short* r0 = qkv + (size_t)s4.x * 384 + 128;
    const unsigned short* r1 = qkv + (size_t)s4.y * 384 + 128;
    const unsigned short* r2 = qkv + (size_t)s4.z * 384 + 128;
    const unsigned short* r3 = qkv + (size_t)s4.w * 384 + 128;
    unsigned int ku0 = *(const unsigned int*)(r0 + lane * 2);
    unsigned int ku1 = *(const unsigned int*)(r1 + lane * 2);
    unsigned int ku2 = *(const unsigned int*)(r2 + lane * 2);
    unsigned int ku3 = *(const unsigned int*)(r3 + lane * 2);
    unsigned int vu0 = *(const unsigned int*)(r0 + 128 + lane * 2);
    unsigned int vu1 = *(const unsigned int*)(r1 + 128 + lane * 2);
    unsigned int vu2 = *(const unsigned int*)(r2 + 128 + lane * 2);
    unsigned int vu3 = *(const unsigned int*)(r3 + 128 + lane * 2);
    float2 k0 = bf2f2(ku0), k1 = bf2f2(ku1), k2 = bf2f2(ku2), k3 = bf2f2(ku3);
    float p0 = k0.x * q2.x + k0.y * q2.y;
    float p1 = k1.x * q2.x + k1.y * q2.y;
    float p2 = k2.x * q2.x + k2.y * q2.y;
    float p3 = k3.x * q2.x + k3.y * q2.y;
    p0 += __shfl_xor(p0, 1); p1 += __shfl_xor(p1, 1);
    p2 += __shfl_xor(p2, 1); p3 += __shfl_xor(p3, 1);
    p0 += __shfl_xor(p0, 2); p1 += __shfl_xor(p1, 2);
    p2 += __shfl_xor(p2, 2); p3 += __shfl_xor(p3, 2);
    p0 += __shfl_xor(p0, 4); p1 += __shfl_xor(p1, 4);
    p2 += __shfl_xor(p2, 4); p3 += __shfl_xor(p3, 4);
    float sc0 = __expf(fminf(fmaxf(p0 * 0.25f, -5.f), 5.f));
    float sc1 = __expf(fminf(fmaxf(p1 * 0.25f, -5.f), 5.f));
    float sc2 = __expf(fminf(fmaxf(p2 * 0.25f, -5.f), 5.f));
    float sc3 = __expf(fminf(fmaxf(p3 * 0.25f, -5.f), 5.f));
    float2 v0 = bf2f2(vu0), v1 = bf2f2(vu1), v2 = bf2f2(vu2), v3 = bf2f2(vu3);
    wx = fmaf(sc0, v0.x, wx); wy = fmaf(sc0, v0.y, wy);
    wx = fmaf(sc1, v1.x, wx); wy = fmaf(sc1, v1.y, wy);
    wx = fmaf(sc2, v2.x, wx); wy = fmaf(sc2, v2.y, wy);
    wx = fmaf(sc3, v3.x, wx); wy = fmaf(sc3, v3.y, wy);
    z += (sc0 + sc1) + (sc2 + sc3);
  }
  for (; j < end; ++j) {
    int s = csr[j];
    const unsigned short* r0 = qkv + (size_t)s * 384 + 128;
    float2 k2 = bf2f2(*(const unsigned int*)(r0 + lane * 2));
    float p = k2.x * q2.x + k2.y * q2.y;
    p += __shfl_xor(p, 1); p += __shfl_xor(p, 2); p += __shfl_xor(p, 4);
    float sc = __expf(fminf(fmaxf(p * 0.25f, -5.f), 5.f));
    float2 v2 = bf2f2(*(const unsigned int*)(r0 + 128 + lane * 2));
    wx = fmaf(sc, v2.x, wx); wy = fmaf(sc, v2.y, wy);
    z += sc;
  }
  float inv = 1.f / (z + 1e-6f);
  unsigned int pack = (unsigned int)f2bf(wx * inv) | ((unsigned int)f2bf(wy * inv) << 16);
  *(unsigned int*)(attn + (size_t)node * DIM + lane * 2) = pack;
}

// ---------------- column mean over nodes (bf16 in, fp32 acc) ----------------
__global__ __launch_bounds__(256) void colmean_kernel(
    const unsigned short* __restrict__ xb, float* __restrict__ mean)
{
  int col = threadIdx.x & 127;
  int half = threadIdx.x >> 7;
  float acc = 0.f;
  for (int r = blockIdx.x * 2 + half; r < N_NODES; r += gridDim.x * 2)
    acc += bf2f(xb[(size_t)r * DIM + col]);
  __shared__ float s[256];
  s[threadIdx.x] = acc;
  __syncthreads();
  if (threadIdx.x < 128) atomicAdd(&mean[col], s[threadIdx.x] + s[threadIdx.x + 128]);
}

// ---------------- readout MLP 128->64->32->10 ----------------
__global__ void readout_kernel(
    const float* __restrict__ mean,
    const float* __restrict__ mW0, const float* __restrict__ mb0,
    const float* __restrict__ mW1, const float* __restrict__ mb1,
    const float* __restrict__ mW2, const float* __restrict__ mb2,
    float* __restrict__ out)
{
  __shared__ float sx[128], h0[64], h1[32];
  int t = threadIdx.x;
  sx[t] = mean[t] * (1.f / (float)N_NODES);
  __syncthreads();
  if (t < 64) {
    float a = mb0[t];
    for (int i = 0; i < 128; i++) a = fmaf(sx[i], mW0[i * 64 + t], a);
    h0[t] = fmaxf(a, 0.f);
  }
  __syncthreads();
  if (t < 32) {
    float a = mb1[t];
    for (int i = 0; i < 64; i++) a = fmaf(h0[i], mW1[i * 32 + t], a);
    h1[t] = fmaxf(a, 0.f);
  }
  __syncthreads();
  if (t < 10) {
    float a = mb2[t];
    for (int i = 0; i < 32; i++) a = fmaf(h1[i], mW2[i * 10 + t], a);
    out[t] = a;
  }
}

extern "C" void kernel_launch(void* const* d_in, const int* in_sizes, int n_in,
                              void* d_out, int out_size, void* d_ws, size_t ws_size,
                              hipStream_t stream) {
  const int*   x_idx = (const int*)d_in[0];
  const int*   eidx  = (const int*)d_in[1];
  const float* emb   = (const float*)d_in[2];
  const float* Wq = (const float*)d_in[3];  const float* bq = (const float*)d_in[4];
  const float* Wk = (const float*)d_in[5];  const float* bk = (const float*)d_in[6];
  const float* Wv = (const float*)d_in[7];  const float* bv = (const float*)d_in[8];
  const float* Wo = (const float*)d_in[9];  const float* bo = (const float*)d_in[10];
  const float* g1 = (const float*)d_in[11]; const float* be1 = (const float*)d_in[12];
  const float* Wf1 = (const float*)d_in[13]; const float* bf1 = (const float*)d_in[14];
  const float* Wf2 = (const float*)d_in[15]; const float* bf2 = (const float*)d_in[16];
  const float* g2 = (const float*)d_in[17]; const float* be2 = (const float*)d_in[18];
  const float* mW0 = (const float*)d_in[19]; const float* mb0 = (const float*)d_in[20];
  const float* mW1 = (const float*)d_in[21]; const float* mb1 = (const float*)d_in[22];
  const float* mW2 = (const float*)d_in[23]; const float* mb2 = (const float*)d_in[24];
  float* out = (float*)d_out;

  const size_t NX = (size_t)N_NODES * DIM;
  unsigned short* xb  = (unsigned short*)d_ws;                // bf16 residual
  unsigned short* qkv = xb + NX;                              // [N,384] bf16
  unsigned short* a   = qkv + (size_t)N_NODES * 384;          // attn out bf16

  unsigned short* wqkv_p = a + NX;                            // 3*128*384 (single)
  unsigned short* wo_p   = wqkv_p + 3 * 128 * 384;            // 3*2*128*128
  unsigned short* wf1_p  = wo_p   + 3 * 2 * 128 * 128;        // 3*2*128*256
  unsigned short* wf2_p  = wf1_p  + 3 * 2 * 128 * 256;        // 3*2*256*128
  unsigned short* wend   = wf2_p  + 3 * 2 * 256 * 128;

  // zeroed region: counts | fill | meanb  (single memset)
  int* counts  = (int*)wend;
  int* fill    = counts + N_NODES;
  float* meanb = (float*)(fill + N_NODES);
  int* offsets = (int*)(meanb + DIM);
  int* bsums   = offsets + N_NODES + 1;
  int* csr     = bsums + 256;

  const int* e0 = eidx;
  const int* e1 = eidx + N_EDGES;

  hipMemsetAsync(counts, 0, (2 * N_NODES + DIM) * sizeof(int), stream);

  prep_weights1<<<24, 256, 0, stream>>>(Wq, wqkv_p, 128, 128, 384, 0, 3);
  prep_weights1<<<24, 256, 0, stream>>>(Wk, wqkv_p, 128, 128, 384, 128, 3);
  prep_weights1<<<24, 256, 0, stream>>>(Wv, wqkv_p, 128, 128, 384, 256, 3);
  prep_weights2<<<24, 256, 0, stream>>>(Wo, wo_p, 128, 128, 128, 0, 3);
  prep_weights2<<<48, 256, 0, stream>>>(Wf1, wf1_p, 128, 256, 256, 0, 3);
  prep_weights2<<<48, 256, 0, stream>>>(Wf2, wf2_p, 256, 128, 128, 0, 3);

  embed_kernel<<<(N_NODES * 32 + 255) / 256, 256, 0, stream>>>(x_idx, emb, xb);
  hist_kernel<<<(N_EDGES + 255) / 256, 256, 0, stream>>>(e1, counts);
  int nblk = (N_NODES + 255) / 256;
  scan_local<<<nblk, 256, 0, stream>>>(counts, offsets, bsums);
  scan_bsums<<<1, 256, 0, stream>>>(bsums, nblk);
  scan_add<<<nblk, 256, 0, stream>>>(offsets, bsums);
  scatter_kernel<<<(N_EDGES + 255) / 256, 256, 0, stream>>>(e0, e1, offsets, fill, csr);

  int gx = (N_NODES + 127) / 128;      // 391 (qkv0)
  int gc = (N_NODES + 63) / 64;        // 782 (chain)
  int nb4 = (N_NODES + 3) / 4;

  // layer 0 QKV
  mfma_gemm_qkv<<<dim3(gx, 3), 256, 0, stream>>>(xb, wqkv_p, bq, bk, bv, qkv, N_NODES);

  for (int l = 0; l < NLAYERS; ++l) {
    const unsigned short* wo_l   = wo_p   + (size_t)l * 2 * 128 * 128;
    const unsigned short* wf1_l  = wf1_p  + (size_t)l * 2 * 128 * 256;
    const unsigned short* wf2_l  = wf2_p  + (size_t)l * 2 * 256 * 128;
    const unsigned short* wqkv_n = wqkv_p + (size_t)(l + 1) * 128 * 384;  // next layer
    const float* bo_l  = bo  + (size_t)l * DIM;
    const float* g1_l  = g1  + (size_t)l * DIM;
    const float* be1_l = be1 + (size_t)l * DIM;
    const float* bf1_l = bf1 + (size_t)l * 2 * DIM;
    const float* bf2_l = bf2 + (size_t)l * DIM;
    const float* g2_l  = g2  + (size_t)l * DIM;
    const float* be2_l = be2 + (size_t)l * DIM;

    attn_kernel<<<nb4, 256, 0, stream>>>(qkv, offsets, csr, a);
    if (l < NLAYERS - 1) {
      chain_kernel<false><<<gc, 256, 0, stream>>>(
          a, xb, qkv, wo_l, bo_l, g1_l, be1_l, wf1_l, bf1_l, wf2_l, bf2_l,
          g2_l, be2_l, wqkv_n,
          bq + (size_t)(l + 1) * DIM, bk + (size_t)(l + 1) * DIM,
          bv + (size_t)(l + 1) * DIM, N_NODES);
    } else {
      chain_kernel<true><<<gc, 256, 0, stream>>>(
          a, xb, qkv, wo_l, bo_l, g1_l, be1_l, wf1_l, bf1_l, wf2_l, bf2_l,
          g2_l, be2_l, wqkv_p, bq, bk, bv, N_NODES);
    }
  }

  colmean_kernel<<<128, 256, 0, stream>>>(xb, meanb);
  readout_kernel<<<1, 128, 0, stream>>>(meanb, mW0, mb0, mW1, mb1, mW2, mb2, out);
}

// Round 7
// 707.751 us; speedup vs baseline: 2.7810x; 1.0164x over previous
//
#include <hip/hip_runtime.h>
#include <hip/hip_bf16.h>

#define N_NODES 50000
#define N_EDGES 800000
#define DIM 128
#define NLAYERS 3

typedef short bf16x8 __attribute__((ext_vector_type(8)));
typedef float floatx4 __attribute__((ext_vector_type(4)));

__device__ __forceinline__ unsigned short f2bf(float f) {
  unsigned int u = __builtin_bit_cast(unsigned int, f);
  return (unsigned short)((u + 0x7FFFu + ((u >> 16) & 1u)) >> 16);
}
__device__ __forceinline__ float bf2f(unsigned short h) {
  return __builtin_bit_cast(float, (unsigned int)h << 16);
}
__device__ __forceinline__ float bfhi(float f, unsigned short& hb) {
  unsigned int u = __builtin_bit_cast(unsigned int, f);
  unsigned int r = (u + 0x7FFFu + ((u >> 16) & 1u)) & 0xFFFF0000u;
  hb = (unsigned short)(r >> 16);
  return __builtin_bit_cast(float, r);
}
__device__ __forceinline__ float2 bf2f2(unsigned int u) {
  float lo = __builtin_bit_cast(float, u << 16);
  float hi = __builtin_bit_cast(float, u & 0xFFFF0000u);
  return make_float2(lo, hi);
}

// ---------------- embedding gather -> bf16 residual ----------------
__global__ __launch_bounds__(256) void embed_kernel(
    const int* __restrict__ idx, const float* __restrict__ emb,
    unsigned short* __restrict__ xb)
{
  int gid = blockIdx.x * 256 + threadIdx.x;
  int n = gid >> 5;
  int c = (gid & 31) << 2;
  if (n >= N_NODES) return;
  int e = idx[n];
  float4 val = *(const float4*)(emb + (size_t)e * DIM + c);
  ushort4 pk;
  pk.x = f2bf(val.x); pk.y = f2bf(val.y); pk.z = f2bf(val.z); pk.w = f2bf(val.w);
  *(ushort4*)(xb + (size_t)n * DIM + c) = pk;
}

// ---------------- CSR build ----------------
__global__ __launch_bounds__(256) void hist_kernel(
    const int* __restrict__ e1, int* __restrict__ counts)
{
  int i = blockIdx.x * 256 + threadIdx.x;
  if (i < N_EDGES) atomicAdd(&counts[e1[i]], 1);
}

__global__ __launch_bounds__(256) void scan_local(
    const int* __restrict__ counts, int* __restrict__ offsets,
    int* __restrict__ bsums)
{
  __shared__ int buf[256];
  int t = threadIdx.x;
  int i = blockIdx.x * 256 + t;
  int v = (i < N_NODES) ? counts[i] : 0;
  buf[t] = v;
  __syncthreads();
  int s = v;
#pragma unroll
  for (int off = 1; off < 256; off <<= 1) {
    int t2 = (t >= off) ? buf[t - off] : 0;
    __syncthreads();
    s += t2;
    buf[t] = s;
    __syncthreads();
  }
  if (i < N_NODES) offsets[i] = s - v;
  if (t == 255) bsums[blockIdx.x] = s;
}

__global__ void scan_bsums(int* __restrict__ bsums, int nblk)
{
  __shared__ int buf[256];
  int t = threadIdx.x;
  int v = (t < nblk) ? bsums[t] : 0;
  buf[t] = v;
  __syncthreads();
  int s = v;
#pragma unroll
  for (int off = 1; off < 256; off <<= 1) {
    int t2 = (t >= off) ? buf[t - off] : 0;
    __syncthreads();
    s += t2;
    buf[t] = s;
    __syncthreads();
  }
  if (t < nblk) bsums[t] = s - v;
}

__global__ __launch_bounds__(256) void scan_add(
    int* __restrict__ offsets, const int* __restrict__ bsums)
{
  int i = blockIdx.x * 256 + threadIdx.x;
  if (i < N_NODES) offsets[i] += bsums[blockIdx.x];
  if (i == 0) offsets[N_NODES] = N_EDGES;
}

__global__ __launch_bounds__(256) void scatter_kernel(
    const int* __restrict__ e0, const int* __restrict__ e1,
    const int* __restrict__ offsets, int* __restrict__ fill,
    int* __restrict__ csr)
{
  int i = blockIdx.x * 256 + threadIdx.x;
  if (i >= N_EDGES) return;
  int d = e1[i];
  int pos = offsets[d] + atomicAdd(&fill[d], 1);
  csr[pos] = e0[i];
}

// ---------------- weight prep ----------------
__global__ __launch_bounds__(256) void prep_weights2(
    const float* __restrict__ W, unsigned short* __restrict__ out,
    int K, int Nsrc, int Ndst, int c0, int L)
{
  int g = blockIdx.x * 256 + threadIdx.x;
  int fragsPerMat = (K / 8) * Nsrc;
  int total = L * fragsPerMat;
  if (g >= total) return;
  int l = g / fragsPerMat;
  int rem = g - l * fragsPerMat;
  int kq = rem / Nsrc;
  int n = rem - kq * Nsrc;
  const float* Wl = W + (size_t)l * K * Nsrc;
  unsigned short* basehi = out + (size_t)l * 2 * K * Ndst + (size_t)(kq * Ndst + c0 + n) * 8;
  unsigned short* baselo = basehi + (size_t)K * Ndst;
#pragma unroll
  for (int j = 0; j < 8; j++) {
    float f = Wl[(size_t)(kq * 8 + j) * Nsrc + n];
    unsigned short hb;
    float hf = bfhi(f, hb);
    basehi[j] = hb;
    baselo[j] = f2bf(f - hf);
  }
}

__global__ __launch_bounds__(256) void prep_weights1(
    const float* __restrict__ W, unsigned short* __restrict__ out,
    int K, int Nsrc, int Ndst, int c0, int L)
{
  int g = blockIdx.x * 256 + threadIdx.x;
  int fragsPerMat = (K / 8) * Nsrc;
  int total = L * fragsPerMat;
  if (g >= total) return;
  int l = g / fragsPerMat;
  int rem = g - l * fragsPerMat;
  int kq = rem / Nsrc;
  int n = rem - kq * Nsrc;
  const float* Wl = W + (size_t)l * K * Nsrc;
  unsigned short* base = out + (size_t)l * K * Ndst + (size_t)(kq * Ndst + c0 + n) * 8;
#pragma unroll
  for (int j = 0; j < 8; j++)
    base[j] = f2bf(Wl[(size_t)(kq * 8 + j) * Nsrc + n]);
}

// ---------------- QKV GEMM (layer 0 only): bf16 A, single-plane W, bf16 out ----------------
__global__ __launch_bounds__(256) void mfma_gemm_qkv(
    const unsigned short* __restrict__ Ab,
    const unsigned short* __restrict__ Wp,
    const float* __restrict__ bq, const float* __restrict__ bk,
    const float* __restrict__ bv,
    unsigned short* __restrict__ out, int nrows)
{
  constexpr int K = 128, N = 384, CT = 8;
  __shared__ unsigned short SW[16 * 128 * 8];   // 32 KB
  int tid = threadIdx.x;
  int c0 = blockIdx.y * 128;
  const float* bias = (blockIdx.y == 0) ? bq : (blockIdx.y == 1) ? bk : bv;
  int wave = tid >> 6, lane = tid & 63;
  int quad = lane >> 4, l16 = lane & 15;
  int row0 = blockIdx.x * 128 + wave * 32;

  floatx4 acc[2][CT];
#pragma unroll
  for (int rt = 0; rt < 2; rt++)
#pragma unroll
    for (int ct = 0; ct < CT; ct++) acc[rt][ct] = (floatx4)(0.f);

  const unsigned short* arow[2];
#pragma unroll
  for (int rt = 0; rt < 2; rt++) {
    int r = min(row0 + rt * 16 + l16, nrows - 1);
    arow[rt] = Ab + (size_t)r * K + quad * 8;
  }
#pragma unroll 4
  for (int f = tid; f < 16 * 128; f += 256) {
    int kq = f >> 7;
    int n = f & 127;
    *(bf16x8*)&SW[f * 8] = *(const bf16x8*)&Wp[(size_t)(kq * N + c0 + n) * 8];
  }
  __syncthreads();
#pragma unroll
  for (int kb = 0; kb < 4; ++kb) {
    bf16x8 av[2];
#pragma unroll
    for (int rt = 0; rt < 2; rt++)
      av[rt] = *(const bf16x8*)(arow[rt] + kb * 32);
#pragma unroll
    for (int ct = 0; ct < CT; ct++) {
      bf16x8 bh = *(bf16x8*)&SW[((kb * 4 + quad) * 128 + ct * 16 + l16) * 8];
#pragma unroll
      for (int rt = 0; rt < 2; rt++)
        acc[rt][ct] = __builtin_amdgcn_mfma_f32_16x16x32_bf16(av[rt], bh, acc[rt][ct], 0, 0, 0);
    }
  }
#pragma unroll
  for (int ct = 0; ct < CT; ct++) {
    float bvv = bias[ct * 16 + l16];
    int col = c0 + ct * 16 + l16;
#pragma unroll
    for (int rt = 0; rt < 2; rt++)
#pragma unroll
      for (int i = 0; i < 4; i++) {
        int r = row0 + rt * 16 + quad * 4 + i;
        if (r < nrows)
          out[(size_t)r * 384 + col] = f2bf(acc[rt][ct][i] + bvv);
      }
  }
}

// ================ fused dense chain: O-GEMM + LN1 + FFN1 + FFN2 + LN2 (+QKV next) ================
// 64 rows/block, 4 waves, each wave owns 16 rows. NO barriers: Y/F LDS slices are
// per-wave private (C-layout -> A-layout transpose is intra-wave). B-fragments are
// read directly from global (frag-major weights, lane-contiguous 16B, L1/L2-resident).
// Y/F row stride 136 ushorts (272 B) -> conflict-free ds_read_b128.
#define LSTR 136
template<bool LAST>
__global__ __launch_bounds__(256) void chain_kernel(
    const unsigned short* __restrict__ a,     // [N,128] attn out
    unsigned short* __restrict__ xb,          // [N,128] residual in (h) / out (x2)
    unsigned short* __restrict__ qkv,         // [N,384] out: next-layer qkv
    const unsigned short* __restrict__ wo, const float* __restrict__ bo,
    const float* __restrict__ g1, const float* __restrict__ be1,
    const unsigned short* __restrict__ wf1, const float* __restrict__ bf1,
    const unsigned short* __restrict__ wf2, const float* __restrict__ bf2,
    const float* __restrict__ g2, const float* __restrict__ be2,
    const unsigned short* __restrict__ wqkv,
    const float* __restrict__ bq, const float* __restrict__ bk,
    const float* __restrict__ bv, int nrows)
{
  __shared__ unsigned short Y[64 * LSTR];  // 17 KB
  __shared__ unsigned short F[64 * LSTR];  // 17 KB
  int tid = threadIdx.x;
  int wave = tid >> 6, lane = tid & 63;
  int quad = lane >> 4, l16 = lane & 15;
  int rbase = blockIdx.x * 64;
  int wrow = wave * 16;
  int colL = l16;  // column base within 16-col tile

  // ---- O-GEMM (K=128, N=128, hi/lo planes) ----
  floatx4 accO[8];
#pragma unroll
  for (int cc = 0; cc < 8; cc++) accO[cc] = (floatx4)(0.f);
  {
    int grA = min(rbase + wrow + l16, nrows - 1);
    const unsigned short* arow = a + (size_t)grA * 128 + quad * 8;
#pragma unroll
    for (int kb = 0; kb < 4; kb++) {
      bf16x8 av = *(const bf16x8*)(arow + kb * 32);
      int kq = kb * 4 + quad;
#pragma unroll
      for (int cc = 0; cc < 8; cc++) {
        const unsigned short* bp = wo + (size_t)(kq * 128 + cc * 16 + colL) * 8;
        bf16x8 bh = *(const bf16x8*)bp;
        bf16x8 bl = *(const bf16x8*)(bp + 128 * 128);
        accO[cc] = __builtin_amdgcn_mfma_f32_16x16x32_bf16(av, bh, accO[cc], 0, 0, 0);
        accO[cc] = __builtin_amdgcn_mfma_f32_16x16x32_bf16(av, bl, accO[cc], 0, 0, 0);
      }
    }
  }

  // ---- LN1: x1 = LN(h + y) (regs); y -> Y ----
  float x1v[8][4];
  {
    float biasO[8], g1v[8], b1v[8];
#pragma unroll
    for (int cc = 0; cc < 8; cc++) {
      int col = cc * 16 + colL;
      biasO[cc] = bo[col]; g1v[cc] = g1[col]; b1v[cc] = be1[col];
    }
#pragma unroll
    for (int i = 0; i < 4; i++) {
      int lrow = wrow + quad * 4 + i;
      int grow = min(rbase + lrow, nrows - 1);
      float t[8]; float s = 0.f;
#pragma unroll
      for (int cc = 0; cc < 8; cc++) {
        float yv = accO[cc][i] + biasO[cc];
        Y[lrow * LSTR + cc * 16 + colL] = f2bf(yv);
        t[cc] = yv + bf2f(xb[(size_t)grow * 128 + cc * 16 + colL]);
        s += t[cc];
      }
      s += __shfl_xor(s, 1); s += __shfl_xor(s, 2);
      s += __shfl_xor(s, 4); s += __shfl_xor(s, 8);
      float mean = s * (1.f / 128.f);
      float vv = 0.f;
#pragma unroll
      for (int cc = 0; cc < 8; cc++) { float d = t[cc] - mean; vv += d * d; }
      vv += __shfl_xor(vv, 1); vv += __shfl_xor(vv, 2);
      vv += __shfl_xor(vv, 4); vv += __shfl_xor(vv, 8);
      float inv = rsqrtf(vv * (1.f / 128.f) + 1e-5f);
#pragma unroll
      for (int cc = 0; cc < 8; cc++)
        x1v[cc][i] = (t[cc] - mean) * inv * g1v[cc] + b1v[cc];
    }
  }

  // ---- FFN1 (K=128,N=256 in two 128-col halves) + FFN2 (K=256 in two halves) ----
  floatx4 acc2[8];
#pragma unroll
  for (int cc = 0; cc < 8; cc++) acc2[cc] = (floatx4)(0.f);
#pragma unroll
  for (int h = 0; h < 2; h++) {
    floatx4 accF[8];
#pragma unroll
    for (int cc = 0; cc < 8; cc++) accF[cc] = (floatx4)(0.f);
#pragma unroll
    for (int kb = 0; kb < 4; kb++) {
      bf16x8 av = *(bf16x8*)&Y[(wrow + l16) * LSTR + kb * 32 + quad * 8];
      int kq = kb * 4 + quad;
#pragma unroll
      for (int cc = 0; cc < 8; cc++) {
        const unsigned short* bp = wf1 + (size_t)(kq * 256 + h * 128 + cc * 16 + colL) * 8;
        bf16x8 bh = *(const bf16x8*)bp;
        bf16x8 bl = *(const bf16x8*)(bp + 128 * 256);
        accF[cc] = __builtin_amdgcn_mfma_f32_16x16x32_bf16(av, bh, accF[cc], 0, 0, 0);
        accF[cc] = __builtin_amdgcn_mfma_f32_16x16x32_bf16(av, bl, accF[cc], 0, 0, 0);
      }
    }
    // relu + bias -> F
#pragma unroll
    for (int i = 0; i < 4; i++) {
      int lrow = wrow + quad * 4 + i;
#pragma unroll
      for (int cc = 0; cc < 8; cc++) {
        float fv = fmaxf(accF[cc][i] + bf1[h * 128 + cc * 16 + colL], 0.f);
        F[lrow * LSTR + cc * 16 + colL] = f2bf(fv);
      }
    }
#pragma unroll
    for (int kb = 0; kb < 4; kb++) {
      bf16x8 av = *(bf16x8*)&F[(wrow + l16) * LSTR + kb * 32 + quad * 8];
      int kq = h * 16 + kb * 4 + quad;
#pragma unroll
      for (int cc = 0; cc < 8; cc++) {
        const unsigned short* bp = wf2 + (size_t)(kq * 128 + cc * 16 + colL) * 8;
        bf16x8 bh = *(const bf16x8*)bp;
        bf16x8 bl = *(const bf16x8*)(bp + 256 * 128);
        acc2[cc] = __builtin_amdgcn_mfma_f32_16x16x32_bf16(av, bh, acc2[cc], 0, 0, 0);
        acc2[cc] = __builtin_amdgcn_mfma_f32_16x16x32_bf16(av, bl, acc2[cc], 0, 0, 0);
      }
    }
  }

  // ---- LN2: x2 = LN(x1 + ffn2) -> xb (global) and Y (for QKV) ----
  {
    float bias2[8], g2v[8], b2v[8];
#pragma unroll
    for (int cc = 0; cc < 8; cc++) {
      int col = cc * 16 + colL;
      bias2[cc] = bf2[col]; g2v[cc] = g2[col]; b2v[cc] = be2[col];
    }
#pragma unroll
    for (int i = 0; i < 4; i++) {
      int lrow = wrow + quad * 4 + i;
      int grow = rbase + lrow;
      float t[8]; float s = 0.f;
#pragma unroll
      for (int cc = 0; cc < 8; cc++) {
        t[cc] = acc2[cc][i] + bias2[cc] + x1v[cc][i];
        s += t[cc];
      }
      s += __shfl_xor(s, 1); s += __shfl_xor(s, 2);
      s += __shfl_xor(s, 4); s += __shfl_xor(s, 8);
      float mean = s * (1.f / 128.f);
      float vv = 0.f;
#pragma unroll
      for (int cc = 0; cc < 8; cc++) { float d = t[cc] - mean; vv += d * d; }
      vv += __shfl_xor(vv, 1); vv += __shfl_xor(vv, 2);
      vv += __shfl_xor(vv, 4); vv += __shfl_xor(vv, 8);
      float inv = rsqrtf(vv * (1.f / 128.f) + 1e-5f);
#pragma unroll
      for (int cc = 0; cc < 8; cc++) {
        float o = (t[cc] - mean) * inv * g2v[cc] + b2v[cc];
        unsigned short ob = f2bf(o);
        Y[lrow * LSTR + cc * 16 + colL] = ob;
        if (grow < nrows) xb[(size_t)grow * 128 + cc * 16 + colL] = ob;
      }
    }
  }

  // ---- QKV for next layer (skipped on last) ----
  if (!LAST) {
#pragma unroll
    for (int c = 0; c < 3; c++) {
      floatx4 accQ[8];
#pragma unroll
      for (int ct = 0; ct < 8; ct++) accQ[ct] = (floatx4)(0.f);
#pragma unroll
      for (int kb = 0; kb < 4; kb++) {
        bf16x8 av = *(bf16x8*)&Y[(wrow + l16) * LSTR + kb * 32 + quad * 8];
        int kq = kb * 4 + quad;
#pragma unroll
        for (int ct = 0; ct < 8; ct++) {
          bf16x8 bh = *(const bf16x8*)&wqkv[(size_t)(kq * 384 + c * 128 + ct * 16 + colL) * 8];
          accQ[ct] = __builtin_amdgcn_mfma_f32_16x16x32_bf16(av, bh, accQ[ct], 0, 0, 0);
        }
      }
      const float* bias = (c == 0) ? bq : (c == 1) ? bk : bv;
#pragma unroll
      for (int ct = 0; ct < 8; ct++) {
        float bvv = bias[ct * 16 + colL];
#pragma unroll
        for (int i = 0; i < 4; i++) {
          int grow = rbase + wrow + quad * 4 + i;
          if (grow < nrows)
            qkv[(size_t)grow * 384 + c * 128 + ct * 16 + colL] = f2bf(accQ[ct][i] + bvv);
        }
      }
    }
  }
}
#undef LSTR

// ---------------- fused edge attention (bf16 qkv), one wave per dst node, x4 unroll ----------------
__global__ __launch_bounds__(256) void attn_kernel(
    const unsigned short* __restrict__ qkv,
    const int* __restrict__ offsets, const int* __restrict__ csr,
    unsigned short* __restrict__ attn)
{
  int node = blockIdx.x * 4 + (threadIdx.x >> 6);
  int lane = threadIdx.x & 63;
  if (node >= N_NODES) return;
  float2 q2 = bf2f2(*(const unsigned int*)(qkv + (size_t)node * 384 + lane * 2));
  float wx = 0.f, wy = 0.f, z = 0.f;
  int j = offsets[node], end = offsets[node + 1];
  for (; j + 4 <= end; j += 4) {
    int4 s4 = *(const int4*)(csr + j);
    const unsigned short* r0 = qkv + (size_t)s4.x * 384 + 128;
    const unsigned short* r1 = qkv + (size_t)s4.y * 384 + 128;
    const unsigned short* r2 = qkv + (size_t)s4.z * 384 + 128;
    const unsigned short* r3 = qkv + (size_t)s4.w * 384 + 128;
    unsigned int ku0 = *(const unsigned int*)(r0 + lane * 2);
    unsigned int ku1 = *(const unsigned int*)(r1 + lane * 2);
    unsigned int ku2 = *(const unsigned int*)(r2 + lane * 2);
    unsigned int ku3 = *(const unsigned int*)(r3 + lane * 2);
    unsigned int vu0 = *(const unsigned int*)(r0 + 128 + lane * 2);
    unsigned int vu1 = *(const unsigned int*)(r1 + 128 + lane * 2);
    unsigned int vu2 = *(const unsigned int*)(r2 + 128 + lane * 2);
    unsigned int vu3 = *(const unsigned int*)(r3 + 128 + lane * 2);
    float2 k0 = bf2f2(ku0), k1 = bf2f2(ku1), k2 = bf2f2(ku2), k3 = bf2f2(ku3);
    float p0 = k0.x * q2.x + k0.y * q2.y;
    float p1 = k1.x * q2.x + k1.y * q2.y;
    float p2 = k2.x * q2.x + k2.y * q2.y;
    float p3 = k3.x * q2.x + k3.y * q2.y;
    p0 += __shfl_xor(p0, 1); p1 += __shfl_xor(p1, 1);
    p2 += __shfl_xor(p2, 1); p3 += __shfl_xor(p3, 1);
    p0 += __shfl_xor(p0, 2); p1 += __shfl_xor(p1, 2);
    p2 += __shfl_xor(p2, 2); p3 += __shfl_xor(p3, 2);
    p0 += __shfl_xor(p0, 4); p1 += __shfl_xor(p1, 4);
    p2 += __shfl_xor(p2, 4); p3 += __shfl_xor(p3, 4);
    float sc0 = __expf(fminf(fmaxf(p0 * 0.25f, -5.f), 5.f));
    float sc1 = __expf(fminf(fmaxf(p1 * 0.25f, -5.f), 5.f));
    float sc2 = __expf(fminf(fmaxf(p2 * 0.25f, -5.f), 5.f));
    float sc3 = __expf(fminf(fmaxf(p3 * 0.25f, -5.f), 5.f));
    float2 v0 = bf2f2(vu0), v1 = bf2f2(vu1), v2 = bf2f2(vu2), v3 = bf2f2(vu3);
    wx = fmaf(sc0, v0.x, wx); wy = fmaf(sc0, v0.y, wy);
    wx = fmaf(sc1, v1.x, wx); wy = fmaf(sc1, v1.y, wy);
    wx = fmaf(sc2, v2.x, wx); wy = fmaf(sc2, v2.y, wy);
    wx = fmaf(sc3, v3.x, wx); wy = fmaf(sc3, v3.y, wy);
    z += (sc0 + sc1) + (sc2 + sc3);
  }
  for (; j < end; ++j) {
    int s = csr[j];
    const unsigned short* r0 = qkv + (size_t)s * 384 + 128;
    float2 k2 = bf2f2(*(const unsigned int*)(r0 + lane * 2));
    float p = k2.x * q2.x + k2.y * q2.y;
    p += __shfl_xor(p, 1); p += __shfl_xor(p, 2); p += __shfl_xor(p, 4);
    float sc = __expf(fminf(fmaxf(p * 0.25f, -5.f), 5.f));
    float2 v2 = bf2f2(*(const unsigned int*)(r0 + 128 + lane * 2));
    wx = fmaf(sc, v2.x, wx); wy = fmaf(sc, v2.y, wy);
    z += sc;
  }
  float inv = 1.f / (z + 1e-6f);
  unsigned int pack = (unsigned int)f2bf(wx * inv) | ((unsigned int)f2bf(wy * inv) << 16);
  *(unsigned int*)(attn + (size_t)node * DIM + lane * 2) = pack;
}

// ---------------- column mean over nodes (bf16 in, fp32 acc) ----------------
__global__ __launch_bounds__(256) void colmean_kernel(
    const unsigned short* __restrict__ xb, float* __restrict__ mean)
{
  int col = threadIdx.x & 127;
  int half = threadIdx.x >> 7;
  float acc = 0.f;
  for (int r = blockIdx.x * 2 + half; r < N_NODES; r += gridDim.x * 2)
    acc += bf2f(xb[(size_t)r * DIM + col]);
  __shared__ float s[256];
  s[threadIdx.x] = acc;
  __syncthreads();
  if (threadIdx.x < 128) atomicAdd(&mean[col], s[threadIdx.x] + s[threadIdx.x + 128]);
}

// ---------------- readout MLP 128->64->32->10 ----------------
__global__ void readout_kernel(
    const float* __restrict__ mean,
    const float* __restrict__ mW0, const float* __restrict__ mb0,
    const float* __restrict__ mW1, const float* __restrict__ mb1,
    const float* __restrict__ mW2, const float* __restrict__ mb2,
    float* __restrict__ out)
{
  __shared__ float sx[128], h0[64], h1[32];
  int t = threadIdx.x;
  sx[t] = mean[t] * (1.f / (float)N_NODES);
  __syncthreads();
  if (t < 64) {
    float a = mb0[t];
    for (int i = 0; i < 128; i++) a = fmaf(sx[i], mW0[i * 64 + t], a);
    h0[t] = fmaxf(a, 0.f);
  }
  __syncthreads();
  if (t < 32) {
    float a = mb1[t];
    for (int i = 0; i < 64; i++) a = fmaf(h0[i], mW1[i * 32 + t], a);
    h1[t] = fmaxf(a, 0.f);
  }
  __syncthreads();
  if (t < 10) {
    float a = mb2[t];
    for (int i = 0; i < 32; i++) a = fmaf(h1[i], mW2[i * 10 + t], a);
    out[t] = a;
  }
}

extern "C" void kernel_launch(void* const* d_in, const int* in_sizes, int n_in,
                              void* d_out, int out_size, void* d_ws, size_t ws_size,
                              hipStream_t stream) {
  const int*   x_idx = (const int*)d_in[0];
  const int*   eidx  = (const int*)d_in[1];
  const float* emb   = (const float*)d_in[2];
  const float* Wq = (const float*)d_in[3];  const float* bq = (const float*)d_in[4];
  const float* Wk = (const float*)d_in[5];  const float* bk = (const float*)d_in[6];
  const float* Wv = (const float*)d_in[7];  const float* bv = (const float*)d_in[8];
  const float* Wo = (const float*)d_in[9];  const float* bo = (const float*)d_in[10];
  const float* g1 = (const float*)d_in[11]; const float* be1 = (const float*)d_in[12];
  const float* Wf1 = (const float*)d_in[13]; const float* bf1 = (const float*)d_in[14];
  const float* Wf2 = (const float*)d_in[15]; const float* bf2 = (const float*)d_in[16];
  const float* g2 = (const float*)d_in[17]; const float* be2 = (const float*)d_in[18];
  const float* mW0 = (const float*)d_in[19]; const float* mb0 = (const float*)d_in[20];
  const float* mW1 = (const float*)d_in[21]; const float* mb1 = (const float*)d_in[22];
  const float* mW2 = (const float*)d_in[23]; const float* mb2 = (const float*)d_in[24];
  float* out = (float*)d_out;

  const size_t NX = (size_t)N_NODES * DIM;
  unsigned short* xb  = (unsigned short*)d_ws;                // bf16 residual
  unsigned short* qkv = xb + NX;                              // [N,384] bf16
  unsigned short* a   = qkv + (size_t)N_NODES * 384;          // attn out bf16

  unsigned short* wqkv_p = a + NX;                            // 3*128*384 (single)
  unsigned short* wo_p   = wqkv_p + 3 * 128 * 384;            // 3*2*128*128
  unsigned short* wf1_p  = wo_p   + 3 * 2 * 128 * 128;        // 3*2*128*256
  unsigned short* wf2_p  = wf1_p  + 3 * 2 * 128 * 256;        // 3*2*256*128
  unsigned short* wend   = wf2_p  + 3 * 2 * 256 * 128;

  // zeroed region: counts | fill | meanb  (single memset)
  int* counts  = (int*)wend;
  int* fill    = counts + N_NODES;
  float* meanb = (float*)(fill + N_NODES);
  int* offsets = (int*)(meanb + DIM);
  int* bsums   = offsets + N_NODES + 1;
  int* csr     = bsums + 256;

  const int* e0 = eidx;
  const int* e1 = eidx + N_EDGES;

  hipMemsetAsync(counts, 0, (2 * N_NODES + DIM) * sizeof(int), stream);

  prep_weights1<<<24, 256, 0, stream>>>(Wq, wqkv_p, 128, 128, 384, 0, 3);
  prep_weights1<<<24, 256, 0, stream>>>(Wk, wqkv_p, 128, 128, 384, 128, 3);
  prep_weights1<<<24, 256, 0, stream>>>(Wv, wqkv_p, 128, 128, 384, 256, 3);
  prep_weights2<<<24, 256, 0, stream>>>(Wo, wo_p, 128, 128, 128, 0, 3);
  prep_weights2<<<48, 256, 0, stream>>>(Wf1, wf1_p, 128, 256, 256, 0, 3);
  prep_weights2<<<48, 256, 0, stream>>>(Wf2, wf2_p, 256, 128, 128, 0, 3);

  embed_kernel<<<(N_NODES * 32 + 255) / 256, 256, 0, stream>>>(x_idx, emb, xb);
  hist_kernel<<<(N_EDGES + 255) / 256, 256, 0, stream>>>(e1, counts);
  int nblk = (N_NODES + 255) / 256;
  scan_local<<<nblk, 256, 0, stream>>>(counts, offsets, bsums);
  scan_bsums<<<1, 256, 0, stream>>>(bsums, nblk);
  scan_add<<<nblk, 256, 0, stream>>>(offsets, bsums);
  scatter_kernel<<<(N_EDGES + 255) / 256, 256, 0, stream>>>(e0, e1, offsets, fill, csr);

  int gx = (N_NODES + 127) / 128;      // 391 (qkv0)
  int gc = (N_NODES + 63) / 64;        // 782 (chain)
  int nb4 = (N_NODES + 3) / 4;

  // layer 0 QKV
  mfma_gemm_qkv<<<dim3(gx, 3), 256, 0, stream>>>(xb, wqkv_p, bq, bk, bv, qkv, N_NODES);

  for (int l = 0; l < NLAYERS; ++l) {
    const unsigned short* wo_l   = wo_p   + (size_t)l * 2 * 128 * 128;
    const unsigned short* wf1_l  = wf1_p  + (size_t)l * 2 * 128 * 256;
    const unsigned short* wf2_l  = wf2_p  + (size_t)l * 2 * 256 * 128;
    const unsigned short* wqkv_n = wqkv_p + (size_t)(l + 1) * 128 * 384;  // next layer
    const float* bo_l  = bo  + (size_t)l * DIM;
    const float* g1_l  = g1  + (size_t)l * DIM;
    const float* be1_l = be1 + (size_t)l * DIM;
    const float* bf1_l = bf1 + (size_t)l * 2 * DIM;
    const float* bf2_l = bf2 + (size_t)l * DIM;
    const float* g2_l  = g2  + (size_t)l * DIM;
    const float* be2_l = be2 + (size_t)l * DIM;

    attn_kernel<<<nb4, 256, 0, stream>>>(qkv, offsets, csr, a);
    if (l < NLAYERS - 1) {
      chain_kernel<false><<<gc, 256, 0, stream>>>(
          a, xb, qkv, wo_l, bo_l, g1_l, be1_l, wf1_l, bf1_l, wf2_l, bf2_l,
          g2_l, be2_l, wqkv_n,
          bq + (size_t)(l + 1) * DIM, bk + (size_t)(l + 1) * DIM,
          bv + (size_t)(l + 1) * DIM, N_NODES);
    } else {
      chain_kernel<true><<<gc, 256, 0, stream>>>(
          a, xb, qkv, wo_l, bo_l, g1_l, be1_l, wf1_l, bf1_l, wf2_l, bf2_l,
          g2_l, be2_l, wqkv_p, bq, bk, bv, N_NODES);
    }
  }

  colmean_kernel<<<128, 256, 0, stream>>>(xb, meanb);
  readout_kernel<<<1, 128, 0, stream>>>(meanb, mW0, mb0, mW1, mb1, mW2, mb2, out);
}